// Round 12
// baseline (438.697 us; speedup 1.0000x reference)
//
#include <hip/hip_runtime.h>

#define M_CODES 512
#define D_EMB 128
#define D4 32       // D_EMB/4
#define MARGIN 5e-5f
#define TOK_BLK 64  // tokens per block

// numpy pairwise sum (n=128): 8 strided accumulators + tree. Non-contractible
// _rn ops so codegen can't fuse mul+add into fma. (R6-validated bit-exact.)
__device__ __forceinline__ float np_pairwise_sumsq128(const float* __restrict__ a,
                                                      float scale) {
    float r[8];
#pragma unroll
    for (int j = 0; j < 8; ++j) {
        float v = __fmul_rn(a[j], scale);
        r[j] = __fmul_rn(v, v);
    }
    for (int i = 8; i < 128; i += 8) {
#pragma unroll
        for (int j = 0; j < 8; ++j) {
            float v = __fmul_rn(a[i + j], scale);
            r[j] = __fadd_rn(r[j], __fmul_rn(v, v));
        }
    }
    return __fadd_rn(__fadd_rn(__fadd_rn(r[0], r[1]), __fadd_rn(r[2], r[3])),
                     __fadd_rn(__fadd_rn(r[4], r[5]), __fadd_rn(r[6], r[7])));
}

// kSZ: zero accw/accc/flagCnt; for m<512 compute sumE_np + embT transpose.
__global__ void kSZ(const float* __restrict__ emb, float* __restrict__ sumE,
                    float* __restrict__ embT, float* __restrict__ accw,
                    float* __restrict__ accc, int* __restrict__ flagCnt) {
    int i = blockIdx.x * 256 + threadIdx.x;
    accw[i] = 0.f;
    if (i < M_CODES) accc[i] = 0.f;
    if (i == 0) *flagCnt = 0;
    if (i < M_CODES) {
        sumE[i] = np_pairwise_sumsq128(emb + (size_t)i * D_EMB, 1.0f);
        const float* er = emb + (size_t)i * D_EMB;
        for (int d = 0; d < D_EMB; ++d) embT[d * M_CODES + i] = er[d];
    }
}

// kA screen: register-tiled. Block = 64 tokens (x in LDS, rotation-swizzled);
// wave w covers codes [w*128, w*128+128) in 4 passes of 32. Lane = tg(16) x
// cg(4): owns 4 tokens x 8 codes with acc[4][8] in VGPRs; dot reduces WITHIN
// the lane. R11 fix: lane tokens t = tg + 16*tt (NOT 4*tg+tt) so the per-
// instruction bank group (k4+t)%8 = (k4+tg)%8 covers all 8 groups -> 2-way
// (= b128 floor) instead of 8-way conflict (R11: 26M conflict cycles).
__global__ __launch_bounds__(256) void kA(const float* __restrict__ x,
                                          const float* __restrict__ xmask,
                                          const float* __restrict__ emb,
                                          const float* __restrict__ sumE,
                                          int* __restrict__ idx_out,
                                          int* __restrict__ flagCnt,
                                          int* __restrict__ flagList,
                                          float* __restrict__ lossW,
                                          float* __restrict__ maskW, int N) {
    __shared__ float4 xT[TOK_BLK * 32];          // 32 KB; slot = (k4 + t) & 31
    __shared__ float mkL[TOK_BLK], xnL[TOK_BLK];
    __shared__ float mgB1[4][TOK_BLK], mgB2[4][TOK_BLK];
    __shared__ int mgBi[4][TOK_BLK];
    int tid = threadIdx.x;
    int tok0 = blockIdx.x * TOK_BLK;

    // ---- stage x*mask into LDS (rotated), compute xnorm via 4-lane shuffle ----
    int st = tid >> 2, sq = tid & 3;
    int tg_ok = (tok0 + st) < N;
    int tr = tg_ok ? (tok0 + st) : (N - 1);
    float mk = xmask[tr];
    const float4* xg = reinterpret_cast<const float4*>(x + (size_t)tr * D_EMB + sq * 32);
    float pn = 0.f;
#pragma unroll
    for (int j = 0; j < 8; ++j) {
        float4 v = xg[j];
        v.x *= mk; v.y *= mk; v.z *= mk; v.w *= mk;
        pn = fmaf(v.x, v.x, pn); pn = fmaf(v.y, v.y, pn);
        pn = fmaf(v.z, v.z, pn); pn = fmaf(v.w, v.w, pn);
        int k4 = sq * 8 + j;
        xT[st * 32 + ((k4 + st) & 31)] = v;
    }
    pn += __shfl_xor(pn, 1, 64);
    pn += __shfl_xor(pn, 2, 64);
    if (sq == 0) { mkL[st] = mk; xnL[st] = pn; }
    __syncthreads();

    // ---- register-tiled distance scan ----
    int wave = tid >> 6, lane = tid & 63;
    int tg = lane & 15, cg = lane >> 4;
    float b1[4], b2[4]; int bi[4];
#pragma unroll
    for (int tt = 0; tt < 4; ++tt) { b1[tt] = 3.4e38f; b2[tt] = 3.4e38f; bi[tt] = 0x7fffffff; }

    for (int p = 0; p < 4; ++p) {
        int cbase = wave * 128 + p * 32 + cg * 8;
        const float* ep = emb + (size_t)cbase * D_EMB;
        float acc[4][8];
#pragma unroll
        for (int tt = 0; tt < 4; ++tt)
#pragma unroll
            for (int cc = 0; cc < 8; ++cc) acc[tt][cc] = 0.f;
#pragma unroll 4
        for (int k4 = 0; k4 < 32; ++k4) {
            float4 xv[4];
#pragma unroll
            for (int tt = 0; tt < 4; ++tt) {
                int t = tg + 16 * tt;
                xv[tt] = xT[t * 32 + ((k4 + t) & 31)];
            }
#pragma unroll
            for (int cc = 0; cc < 8; ++cc) {
                float4 ev = *reinterpret_cast<const float4*>(ep + cc * D_EMB + k4 * 4);
#pragma unroll
                for (int tt = 0; tt < 4; ++tt) {
                    acc[tt][cc] = fmaf(xv[tt].x, ev.x, acc[tt][cc]);
                    acc[tt][cc] = fmaf(xv[tt].y, ev.y, acc[tt][cc]);
                    acc[tt][cc] = fmaf(xv[tt].z, ev.z, acc[tt][cc]);
                    acc[tt][cc] = fmaf(xv[tt].w, ev.w, acc[tt][cc]);
                }
            }
        }
#pragma unroll
        for (int cc = 0; cc < 8; ++cc) {
            int c = cbase + cc;
            float sE = sumE[c];
#pragma unroll
            for (int tt = 0; tt < 4; ++tt) {
                float s = fmaf(-2.f, acc[tt][cc], sE);
                if (s < b1[tt]) { b2[tt] = b1[tt]; b1[tt] = s; bi[tt] = c; }
                else if (s < b2[tt]) b2[tt] = s;
            }
        }
    }
    // ---- merge across cg (lane bits 4,5) ----
#pragma unroll
    for (int off = 16; off <= 32; off <<= 1) {
#pragma unroll
        for (int tt = 0; tt < 4; ++tt) {
            float ob1 = __shfl_xor(b1[tt], off, 64);
            float ob2 = __shfl_xor(b2[tt], off, 64);
            int obi = __shfl_xor(bi[tt], off, 64);
            if (ob1 < b1[tt] || (ob1 == b1[tt] && obi < bi[tt])) {
                b2[tt] = fminf(ob2, b1[tt]); b1[tt] = ob1; bi[tt] = obi;
            } else {
                b2[tt] = fminf(b2[tt], ob1);
            }
        }
    }
    if (lane < 16) {
#pragma unroll
        for (int tt = 0; tt < 4; ++tt) {
            int tk = tg + 16 * tt;
            mgB1[wave][tk] = b1[tt];
            mgB2[wave][tk] = b2[tt];
            mgBi[wave][tk] = bi[tt];
        }
    }
    __syncthreads();
    // ---- final merge + outputs by wave 0 (token = lane) ----
    if (tid < TOK_BLK) {
        float f1 = 3.4e38f, f2 = 3.4e38f; int fi = 0x7fffffff;
#pragma unroll
        for (int w = 0; w < 4; ++w) {
            float ob1 = mgB1[w][tid], ob2 = mgB2[w][tid];
            int obi = mgBi[w][tid];
            if (ob1 < f1 || (ob1 == f1 && obi < fi)) {
                f2 = fminf(ob2, f1); f1 = ob1; fi = obi;
            } else {
                f2 = fminf(f2, ob1);
            }
        }
        int tok = tok0 + tid;
        float li = 0.f, mr = 0.f;
        if (tok < N) {
            idx_out[tok] = fi;
            if (f2 - f1 < MARGIN) {
                int pp = atomicAdd(flagCnt, 1);
                flagList[pp] = tok;
            }
            float m2 = mkL[tid];
            li = m2 * m2 * (xnL[tid] + f1);
            mr = m2;
        }
#pragma unroll
        for (int off = 1; off < 64; off <<= 1) {
            li += __shfl_xor(li, off, 64);
            mr += __shfl_xor(mr, off, 64);
        }
        if (tid == 0) { lossW[blockIdx.x] = li; maskW[blockIdx.x] = mr; }
    }
}

// kF: bit-exact np-f32 full rescan for flagged tokens, one wave/token.
__global__ __launch_bounds__(256) void kF(const float* __restrict__ x,
                                          const float* __restrict__ xmask,
                                          const float* __restrict__ embT,
                                          const float* __restrict__ sumE,
                                          const int* __restrict__ flagCnt,
                                          const int* __restrict__ flagList,
                                          int* __restrict__ idx_out) {
    int wave = (blockIdx.x * 256 + threadIdx.x) >> 6;
    int lane = threadIdx.x & 63;
    int nW = gridDim.x * 4;
    int cnt = *flagCnt;
    for (int j = wave; j < cnt; j += nW) {
        int t = flagList[j];
        float mk = xmask[t];
        const float* xr = x + (size_t)t * D_EMB;
        float sx = np_pairwise_sumsq128(xr, mk);
        float best = 3.4e38f;
        int bi = 0x7fffffff;
        for (int cb = 0; cb < 8; ++cb) {
            int c = cb * 64 + lane;
            float acc = 0.f;
            for (int i = 0; i < D_EMB; ++i) {
                float xi = __fmul_rn(xr[i], mk);
                acc = __fmaf_rn(xi, embT[i * M_CODES + c], acc);
            }
            float d = __fsub_rn(__fadd_rn(sumE[c], sx), __fmul_rn(2.f, acc));
            if (d < best || (d == best && c < bi)) { best = d; bi = c; }
        }
#pragma unroll
        for (int off = 32; off > 0; off >>= 1) {
            float s2 = __shfl_xor(best, off, 64);
            int i2 = __shfl_xor(bi, off, 64);
            if (s2 < best || (s2 == best && i2 < bi)) { best = s2; bi = i2; }
        }
        if (lane == 0) idx_out[t] = bi;
    }
}

// kQB: fused gather + scatter. Thread = (token, d4): write q_st (coalesced)
// and 4 global f32 atomics into accw; d4==0 lane bumps the count.
__global__ __launch_bounds__(256) void kQB(const float* __restrict__ x,
                                           const float* __restrict__ emb,
                                           const float* __restrict__ xmask,
                                           const int* __restrict__ idx,
                                           float* __restrict__ q_st,
                                           float* __restrict__ accw,
                                           float* __restrict__ accc, int N) {
    int g = blockIdx.x * 256 + threadIdx.x;
    int t = g >> 5;
    int d4 = g & 31;
    if (t < N) {
        int id = idx[t];
        float mk = xmask[t];
        const float4* E4 = reinterpret_cast<const float4*>(emb);
        float4 ev = E4[(size_t)id * D4 + d4];
        float4 o;
        o.x = ev.x * mk; o.y = ev.y * mk; o.z = ev.z * mk; o.w = ev.w * mk;
        reinterpret_cast<float4*>(q_st)[(size_t)t * D4 + d4] = o;
        float4 v = reinterpret_cast<const float4*>(x + (size_t)t * D_EMB)[d4];
        float* dst = accw + (size_t)id * D_EMB + d4 * 4;
        atomicAdd(dst + 0, v.x * mk);
        atomicAdd(dst + 1, v.y * mk);
        atomicAdd(dst + 2, v.z * mk);
        atomicAdd(dst + 3, v.w * mk);
        if (d4 == 0) atomicAdd(accc + id, 1.0f);
    }
}

// kC: count normalization + loss finalize.
__global__ __launch_bounds__(512) void kC(const float* __restrict__ counts,
                                          const float* __restrict__ ema_count,
                                          float* __restrict__ new_count_out,
                                          float* __restrict__ norm_ws,
                                          const float* __restrict__ lossP,
                                          const float* __restrict__ maskP,
                                          float* __restrict__ loss_out, int nP) {
    __shared__ float red[512];
    int t = threadIdx.x;
    float raw = 0.999f * ema_count[t] + 0.001f * counts[t];
    red[t] = raw;
    __syncthreads();
#pragma unroll
    for (int s = 256; s > 0; s >>= 1) {
        if (t < s) red[t] += red[t + s];
        __syncthreads();
    }
    float nsum = red[0];
    __syncthreads();
    float norm = (raw + 1e-5f) / (nsum + (float)M_CODES * 1e-5f) * nsum;
    new_count_out[t] = norm;
    norm_ws[t] = norm;

    float lp = 0.f, mp = 0.f;
    for (int i = t; i < nP; i += 512) { lp += lossP[i]; mp += maskP[i]; }
    red[t] = lp;
    __syncthreads();
#pragma unroll
    for (int s = 256; s > 0; s >>= 1) {
        if (t < s) red[t] += red[t + s];
        __syncthreads();
    }
    float S = red[0];
    __syncthreads();
    red[t] = mp;
    __syncthreads();
#pragma unroll
    for (int s = 256; s > 0; s >>= 1) {
        if (t < s) red[t] += red[t + s];
        __syncthreads();
    }
    if (t == 0) loss_out[0] = 0.25f * S / (red[0] * (float)D_EMB);
}

// kWD: new_w = 0.999*ema_w + 0.001*accw ; new_emb = new_w / norm[m]
__global__ void kWD(const float* __restrict__ accw, const float* __restrict__ ema_w,
                    const float* __restrict__ norm_ws, float* __restrict__ new_w,
                    float* __restrict__ new_emb) {
    int i = blockIdx.x * 256 + threadIdx.x;
    float w = 0.999f * ema_w[i] + 0.001f * accw[i];
    new_w[i] = w;
    new_emb[i] = w / norm_ws[i >> 7];
}

extern "C" void kernel_launch(void* const* d_in, const int* in_sizes, int n_in,
                              void* d_out, int out_size, void* d_ws, size_t ws_size,
                              hipStream_t stream) {
    const float* x = (const float*)d_in[0];
    const float* xmask = (const float*)d_in[1];
    const float* emb = (const float*)d_in[2];
    const float* ema_count = (const float*)d_in[3];
    const float* ema_weight = (const float*)d_in[4];
    int N = in_sizes[0] / D_EMB;

    float* out = (float*)d_out;
    float* q_st = out;
    float* loss = out + (size_t)N * D_EMB;
    float* new_emb = loss + 1;
    float* new_cnt = new_emb + M_CODES * D_EMB;
    float* new_w = new_cnt + M_CODES;

    char* ws = (char*)d_ws;
    int nBlk = (N + TOK_BLK - 1) / TOK_BLK;   // 1024
    float* fws = (float*)ws;
    int* idx = (int*)fws;                     // N
    float* counts = fws + N;                  // 512 (accc)
    float* norm = counts + M_CODES;           // 512
    float* lossP = norm + M_CODES;            // nBlk
    float* maskP = lossP + nBlk;              // nBlk
    float* sumE = maskP + nBlk;               // 512
    int* flagCnt = (int*)(sumE + M_CODES);    // 2
    int* flagList = flagCnt + 2;              // N
    float* embT = (float*)(flagList + N);     // 65536
    float* accw = embT + M_CODES * D_EMB;     // 65536

    hipLaunchKernelGGL(kSZ, dim3(M_CODES * D_EMB / 256), dim3(256), 0, stream,
                       emb, sumE, embT, accw, counts, flagCnt);
    hipLaunchKernelGGL(kA, dim3(nBlk), dim3(256), 0, stream, x, xmask, emb,
                       sumE, idx, flagCnt, flagList, lossP, maskP, N);
    hipLaunchKernelGGL(kF, dim3(512), dim3(256), 0, stream, x, xmask, embT, sumE,
                       flagCnt, flagList, idx);
    hipLaunchKernelGGL(kQB, dim3((N * 32 + 255) / 256), dim3(256), 0, stream, x,
                       emb, xmask, idx, q_st, accw, counts, N);
    hipLaunchKernelGGL(kC, dim3(1), dim3(512), 0, stream, counts, ema_count,
                       new_cnt, norm, lossP, maskP, loss, nBlk);
    hipLaunchKernelGGL(kWD, dim3(M_CODES * D_EMB / 256), dim3(256), 0, stream,
                       accw, ema_weight, norm, new_w, new_emb);
}

// Round 13
// 389.525 us; speedup vs baseline: 1.1262x; 1.1262x over previous
//
#include <hip/hip_runtime.h>

#define M_CODES 512
#define D_EMB 128
#define D4 32
#define MARGIN 5e-5f

typedef short bf16x8 __attribute__((ext_vector_type(8)));
typedef float f32x4 __attribute__((ext_vector_type(4)));

__device__ __forceinline__ unsigned short f2bf(float f) {  // RNE f32->bf16
    unsigned u = __float_as_uint(f);
    u += 0x7fffu + ((u >> 16) & 1u);
    return (unsigned short)(u >> 16);
}
__device__ __forceinline__ float bf2f(unsigned short h) {
    return __uint_as_float(((unsigned)h) << 16);
}

// numpy pairwise sum (n=128): 8 strided accumulators + tree. Non-contractible
// _rn ops so codegen can't fuse mul+add into fma. (R6-validated bit-exact.)
__device__ __forceinline__ float np_pairwise_sumsq128(const float* __restrict__ a,
                                                      float scale) {
    float r[8];
#pragma unroll
    for (int j = 0; j < 8; ++j) {
        float v = __fmul_rn(a[j], scale);
        r[j] = __fmul_rn(v, v);
    }
    for (int i = 8; i < 128; i += 8) {
#pragma unroll
        for (int j = 0; j < 8; ++j) {
            float v = __fmul_rn(a[i + j], scale);
            r[j] = __fadd_rn(r[j], __fmul_rn(v, v));
        }
    }
    return __fadd_rn(__fadd_rn(__fadd_rn(r[0], r[1]), __fadd_rn(r[2], r[3])),
                     __fadd_rn(__fadd_rn(r[4], r[5]), __fadd_rn(r[6], r[7])));
}

// kSZ: zero accw/accc/flagCnt; for m<512: sumE_np, embT (f32 transpose for kF),
// and split-bf16 codebook ebh/ebl (e = eh + el, |el|<=2^-9|e|).
__global__ void kSZ(const float* __restrict__ emb, float* __restrict__ sumE,
                    float* __restrict__ embT, unsigned short* __restrict__ ebh,
                    unsigned short* __restrict__ ebl, float* __restrict__ accw,
                    float* __restrict__ accc, int* __restrict__ flagCnt) {
    int i = blockIdx.x * 256 + threadIdx.x;
    accw[i] = 0.f;
    if (i < M_CODES) accc[i] = 0.f;
    if (i == 0) *flagCnt = 0;
    if (i < M_CODES) {
        sumE[i] = np_pairwise_sumsq128(emb + (size_t)i * D_EMB, 1.0f);
        const float* er = emb + (size_t)i * D_EMB;
        for (int d = 0; d < D_EMB; ++d) {
            float e = er[d];
            embT[d * M_CODES + i] = e;
            unsigned short hh = f2bf(e);
            ebh[i * D_EMB + d] = hh;
            ebl[i * D_EMB + d] = f2bf(e - bf2f(hh));
        }
    }
}

// kA screen via split-bf16 MFMA (16x16x32, guide-verified C/D layout).
// Wave = 16 tokens x all 512 codes (32 col-tiles x 4 k-steps).
// score = sumE - 2*(xh.eh + xh.el + xl.eh); residual ~3e-6 << MARGIN.
// A-frag built in-lane from f32 x (lane m=lane&15 -> row, kg=lane>>4 -> k-chunk).
__global__ __launch_bounds__(256) void kA(const float* __restrict__ x,
                                          const float* __restrict__ xmask,
                                          const unsigned short* __restrict__ ebh,
                                          const unsigned short* __restrict__ ebl,
                                          const float* __restrict__ sumE,
                                          int* __restrict__ idx_out,
                                          int* __restrict__ flagCnt,
                                          int* __restrict__ flagList,
                                          float* __restrict__ lossW,
                                          float* __restrict__ maskW, int N) {
    __shared__ float xnS[4][16], mkS[4][16];
    int tid = threadIdx.x;
    int wid = tid >> 6, lane = tid & 63;
    int m = lane & 15, kg = lane >> 4;
    int grp = blockIdx.x * 4 + wid;
    int tok0 = grp * 16;
    int tokA = tok0 + m;  // N is a multiple of 16; grid exact -> no guard
    float mk = xmask[tokA];

    bf16x8 ah[4], al[4];
    float xn = 0.f;
#pragma unroll
    for (int ks = 0; ks < 4; ++ks) {
        const float4* p = reinterpret_cast<const float4*>(
            x + (size_t)tokA * D_EMB + ks * 32 + kg * 8);
        float4 v0 = p[0], v1 = p[1];
        float e[8] = {v0.x, v0.y, v0.z, v0.w, v1.x, v1.y, v1.z, v1.w};
        bf16x8 hh, ll;
#pragma unroll
        for (int j = 0; j < 8; ++j) {
            float xv = e[j] * mk;
            xn = fmaf(xv, xv, xn);
            unsigned short h = f2bf(xv);
            hh[j] = (short)h;
            ll[j] = (short)f2bf(xv - bf2f(h));
        }
        ah[ks] = hh;
        al[ks] = ll;
    }
    xn += __shfl_xor(xn, 16, 64);
    xn += __shfl_xor(xn, 32, 64);
    if (kg == 0) { xnS[wid][m] = xn; mkS[wid][m] = mk; }

    float b1[4], b2[4];
    int bi[4];
#pragma unroll
    for (int r = 0; r < 4; ++r) { b1[r] = 3.4e38f; b2[r] = 3.4e38f; bi[r] = 0x7fffffff; }

    for (int ct = 0; ct < 32; ++ct) {
        const bf16x8* bhp = reinterpret_cast<const bf16x8*>(
            ebh + (size_t)(ct * 16 + m) * D_EMB + kg * 8);
        const bf16x8* blp = reinterpret_cast<const bf16x8*>(
            ebl + (size_t)(ct * 16 + m) * D_EMB + kg * 8);
        f32x4 accA = {0.f, 0.f, 0.f, 0.f}, accB = {0.f, 0.f, 0.f, 0.f};
#pragma unroll
        for (int ks = 0; ks < 2; ++ks) {
            bf16x8 bh = bhp[ks * 4], bl = blp[ks * 4];  // +ks*32 ushorts
            accA = __builtin_amdgcn_mfma_f32_16x16x32_bf16(ah[ks], bh, accA, 0, 0, 0);
            accA = __builtin_amdgcn_mfma_f32_16x16x32_bf16(al[ks], bh, accA, 0, 0, 0);
            accA = __builtin_amdgcn_mfma_f32_16x16x32_bf16(ah[ks], bl, accA, 0, 0, 0);
        }
#pragma unroll
        for (int ks = 2; ks < 4; ++ks) {
            bf16x8 bh = bhp[ks * 4], bl = blp[ks * 4];
            accB = __builtin_amdgcn_mfma_f32_16x16x32_bf16(ah[ks], bh, accB, 0, 0, 0);
            accB = __builtin_amdgcn_mfma_f32_16x16x32_bf16(al[ks], bh, accB, 0, 0, 0);
            accB = __builtin_amdgcn_mfma_f32_16x16x32_bf16(ah[ks], bl, accB, 0, 0, 0);
        }
        int c = ct * 16 + m;          // C/D col = lane&15 (verified layout)
        float sE = sumE[c];
#pragma unroll
        for (int r = 0; r < 4; ++r) {  // C/D row = kg*4 + r (verified layout)
            float s = fmaf(-2.f, accA[r] + accB[r], sE);
            if (s < b1[r]) { b2[r] = b1[r]; b1[r] = s; bi[r] = c; }
            else if (s < b2[r]) b2[r] = s;
        }
    }
    // merge across the 16 col-lanes (same 4 token rows within a kg group)
#pragma unroll
    for (int off = 1; off <= 8; off <<= 1) {
#pragma unroll
        for (int r = 0; r < 4; ++r) {
            float o1 = __shfl_xor(b1[r], off, 64);
            float o2 = __shfl_xor(b2[r], off, 64);
            int oi = __shfl_xor(bi[r], off, 64);
            if (o1 < b1[r] || (o1 == b1[r] && oi < bi[r])) {
                b2[r] = fminf(b1[r], o2); b1[r] = o1; bi[r] = oi;
            } else {
                b2[r] = fminf(b2[r], o1);
            }
        }
    }
    __syncthreads();
    float liS = 0.f, mkT = 0.f;
#pragma unroll
    for (int r = 0; r < 4; ++r) {
        int row = kg * 4 + r;
        float mkr = mkS[wid][row], xnr = xnS[wid][row];
        liS += mkr * mkr * (xnr + b1[r]);
        mkT += mkr;
        if (m == 0) {
            int tokr = tok0 + row;
            idx_out[tokr] = bi[r];
            if (b2[r] - b1[r] < MARGIN) {
                int pp = atomicAdd(flagCnt, 1);
                flagList[pp] = tokr;
            }
        }
    }
    liS += __shfl_xor(liS, 16, 64);
    liS += __shfl_xor(liS, 32, 64);
    mkT += __shfl_xor(mkT, 16, 64);
    mkT += __shfl_xor(mkT, 32, 64);
    if (lane == 0) { lossW[grp] = liS; maskW[grp] = mkT; }
}

// kF: bit-exact np-f32 rescan for flagged tokens, 4 tokens per wave
// (shared embT reads). Per (token,cb): sequential __fmaf_rn chain over i.
__global__ __launch_bounds__(256) void kF(const float* __restrict__ x,
                                          const float* __restrict__ xmask,
                                          const float* __restrict__ embT,
                                          const float* __restrict__ sumE,
                                          const int* __restrict__ flagCnt,
                                          const int* __restrict__ flagList,
                                          int* __restrict__ idx_out) {
    int wave = (blockIdx.x * 256 + threadIdx.x) >> 6;
    int lane = threadIdx.x & 63;
    int nW = gridDim.x * 4;
    int cnt = *flagCnt;
    for (int j = wave * 4; j < cnt; j += nW * 4) {
        int t[4]; float mk[4], sx[4];
#pragma unroll
        for (int q = 0; q < 4; ++q) {
            int jj = (j + q < cnt) ? (j + q) : j;
            t[q] = flagList[jj];
            mk[q] = xmask[t[q]];
            sx[q] = np_pairwise_sumsq128(x + (size_t)t[q] * D_EMB, mk[q]);
        }
        float acc[4][8];
#pragma unroll
        for (int q = 0; q < 4; ++q)
#pragma unroll
            for (int cb = 0; cb < 8; ++cb) acc[q][cb] = 0.f;
        for (int i = 0; i < D_EMB; ++i) {
            float ev[8];
#pragma unroll
            for (int cb = 0; cb < 8; ++cb) ev[cb] = embT[i * M_CODES + cb * 64 + lane];
            float xq[4];
#pragma unroll
            for (int q = 0; q < 4; ++q) xq[q] = __fmul_rn(x[(size_t)t[q] * D_EMB + i], mk[q]);
#pragma unroll
            for (int q = 0; q < 4; ++q)
#pragma unroll
                for (int cb = 0; cb < 8; ++cb)
                    acc[q][cb] = __fmaf_rn(xq[q], ev[cb], acc[q][cb]);
        }
#pragma unroll
        for (int q = 0; q < 4; ++q) {
            float best = 3.4e38f;
            int bq = 0x7fffffff;
#pragma unroll
            for (int cb = 0; cb < 8; ++cb) {
                int c = cb * 64 + lane;
                float d = __fsub_rn(__fadd_rn(sumE[c], sx[q]), __fmul_rn(2.f, acc[q][cb]));
                if (d < best || (d == best && c < bq)) { best = d; bq = c; }
            }
#pragma unroll
            for (int off = 32; off > 0; off >>= 1) {
                float s2 = __shfl_xor(best, off, 64);
                int i2 = __shfl_xor(bq, off, 64);
                if (s2 < best || (s2 == best && i2 < bq)) { best = s2; bq = i2; }
            }
            if (lane == 0) idx_out[t[q]] = bq;
        }
    }
}

// kQB: fused gather + scatter. Thread = (token, d4): write q_st (coalesced)
// and 4 global f32 atomics into accw; d4==0 lane bumps the count.
__global__ __launch_bounds__(256) void kQB(const float* __restrict__ x,
                                           const float* __restrict__ emb,
                                           const float* __restrict__ xmask,
                                           const int* __restrict__ idx,
                                           float* __restrict__ q_st,
                                           float* __restrict__ accw,
                                           float* __restrict__ accc, int N) {
    int g = blockIdx.x * 256 + threadIdx.x;
    int t = g >> 5;
    int d4 = g & 31;
    if (t < N) {
        int id = idx[t];
        float mk = xmask[t];
        const float4* E4 = reinterpret_cast<const float4*>(emb);
        float4 ev = E4[(size_t)id * D4 + d4];
        float4 o;
        o.x = ev.x * mk; o.y = ev.y * mk; o.z = ev.z * mk; o.w = ev.w * mk;
        reinterpret_cast<float4*>(q_st)[(size_t)t * D4 + d4] = o;
        float4 v = reinterpret_cast<const float4*>(x + (size_t)t * D_EMB)[d4];
        float* dst = accw + (size_t)id * D_EMB + d4 * 4;
        atomicAdd(dst + 0, v.x * mk);
        atomicAdd(dst + 1, v.y * mk);
        atomicAdd(dst + 2, v.z * mk);
        atomicAdd(dst + 3, v.w * mk);
        if (d4 == 0) atomicAdd(accc + id, 1.0f);
    }
}

// kC: count normalization + loss finalize.
__global__ __launch_bounds__(512) void kC(const float* __restrict__ counts,
                                          const float* __restrict__ ema_count,
                                          float* __restrict__ new_count_out,
                                          float* __restrict__ norm_ws,
                                          const float* __restrict__ lossP,
                                          const float* __restrict__ maskP,
                                          float* __restrict__ loss_out, int nP) {
    __shared__ float red[512];
    int t = threadIdx.x;
    float raw = 0.999f * ema_count[t] + 0.001f * counts[t];
    red[t] = raw;
    __syncthreads();
#pragma unroll
    for (int s = 256; s > 0; s >>= 1) {
        if (t < s) red[t] += red[t + s];
        __syncthreads();
    }
    float nsum = red[0];
    __syncthreads();
    float norm = (raw + 1e-5f) / (nsum + (float)M_CODES * 1e-5f) * nsum;
    new_count_out[t] = norm;
    norm_ws[t] = norm;

    float lp = 0.f, mp = 0.f;
    for (int i = t; i < nP; i += 512) { lp += lossP[i]; mp += maskP[i]; }
    red[t] = lp;
    __syncthreads();
#pragma unroll
    for (int s = 256; s > 0; s >>= 1) {
        if (t < s) red[t] += red[t + s];
        __syncthreads();
    }
    float S = red[0];
    __syncthreads();
    red[t] = mp;
    __syncthreads();
#pragma unroll
    for (int s = 256; s > 0; s >>= 1) {
        if (t < s) red[t] += red[t + s];
        __syncthreads();
    }
    if (t == 0) loss_out[0] = 0.25f * S / (red[0] * (float)D_EMB);
}

// kWD: new_w = 0.999*ema_w + 0.001*accw ; new_emb = new_w / norm[m]
__global__ void kWD(const float* __restrict__ accw, const float* __restrict__ ema_w,
                    const float* __restrict__ norm_ws, float* __restrict__ new_w,
                    float* __restrict__ new_emb) {
    int i = blockIdx.x * 256 + threadIdx.x;
    float w = 0.999f * ema_w[i] + 0.001f * accw[i];
    new_w[i] = w;
    new_emb[i] = w / norm_ws[i >> 7];
}

extern "C" void kernel_launch(void* const* d_in, const int* in_sizes, int n_in,
                              void* d_out, int out_size, void* d_ws, size_t ws_size,
                              hipStream_t stream) {
    const float* x = (const float*)d_in[0];
    const float* xmask = (const float*)d_in[1];
    const float* emb = (const float*)d_in[2];
    const float* ema_count = (const float*)d_in[3];
    const float* ema_weight = (const float*)d_in[4];
    int N = in_sizes[0] / D_EMB;

    float* out = (float*)d_out;
    float* q_st = out;
    float* loss = out + (size_t)N * D_EMB;
    float* new_emb = loss + 1;
    float* new_cnt = new_emb + M_CODES * D_EMB;
    float* new_w = new_cnt + M_CODES;

    int nGrp = N / 16;                         // 4096 groups (16 tokens each)
    float* fws = (float*)d_ws;
    int* idx = (int*)fws;                      // N
    float* counts = fws + N;                   // 512 (accc)
    float* norm = counts + M_CODES;            // 512
    float* lossP = norm + M_CODES;             // nGrp
    float* maskP = lossP + nGrp;               // nGrp
    float* sumE = maskP + nGrp;                // 512
    int* flagCnt = (int*)(sumE + M_CODES);     // 4 (pad keeps 16B alignment)
    int* flagList = flagCnt + 4;               // N
    float* embT = (float*)(flagList + N);      // 65536
    float* accw = embT + M_CODES * D_EMB;      // 65536
    unsigned short* ebh = (unsigned short*)(accw + M_CODES * D_EMB);  // 65536 u16
    unsigned short* ebl = ebh + M_CODES * D_EMB;                      // 65536 u16

    hipLaunchKernelGGL(kSZ, dim3(M_CODES * D_EMB / 256), dim3(256), 0, stream,
                       emb, sumE, embT, ebh, ebl, accw, counts, flagCnt);
    hipLaunchKernelGGL(kA, dim3(nGrp / 4), dim3(256), 0, stream, x, xmask, ebh,
                       ebl, sumE, idx, flagCnt, flagList, lossP, maskP, N);
    hipLaunchKernelGGL(kF, dim3(512), dim3(256), 0, stream, x, xmask, embT, sumE,
                       flagCnt, flagList, idx);
    hipLaunchKernelGGL(kQB, dim3((N * 32 + 255) / 256), dim3(256), 0, stream, x,
                       emb, xmask, idx, q_st, accw, counts, N);
    hipLaunchKernelGGL(kC, dim3(1), dim3(512), 0, stream, counts, ema_count,
                       new_cnt, norm, lossP, maskP, loss, nGrp);
    hipLaunchKernelGGL(kWD, dim3(M_CODES * D_EMB / 256), dim3(256), 0, stream,
                       accw, ema_weight, norm, new_w, new_emb);
}

// Round 15
// 320.520 us; speedup vs baseline: 1.3687x; 1.2153x over previous
//
#include <hip/hip_runtime.h>

#define M_CODES 512
#define D_EMB 128
#define D4 32
#define MARGIN 5e-5f
#define SCHUNK 2048   // tokens per scatter block

typedef short bf16x8 __attribute__((ext_vector_type(8)));
typedef float f32x4 __attribute__((ext_vector_type(4)));

__device__ __forceinline__ unsigned short f2bf(float f) {  // RNE f32->bf16
    unsigned u = __float_as_uint(f);
    u += 0x7fffu + ((u >> 16) & 1u);
    return (unsigned short)(u >> 16);
}
__device__ __forceinline__ float bf2f(unsigned short h) {
    return __uint_as_float(((unsigned)h) << 16);
}

// numpy pairwise sum (n=128): 8 strided accumulators + tree. (R6-validated.)
__device__ __forceinline__ float np_pairwise_sumsq128(const float* __restrict__ a,
                                                      float scale) {
    float r[8];
#pragma unroll
    for (int j = 0; j < 8; ++j) {
        float v = __fmul_rn(a[j], scale);
        r[j] = __fmul_rn(v, v);
    }
    for (int i = 8; i < 128; i += 8) {
#pragma unroll
        for (int j = 0; j < 8; ++j) {
            float v = __fmul_rn(a[i + j], scale);
            r[j] = __fadd_rn(r[j], __fmul_rn(v, v));
        }
    }
    return __fadd_rn(__fadd_rn(__fadd_rn(r[0], r[1]), __fadd_rn(r[2], r[3])),
                     __fadd_rn(__fadd_rn(r[4], r[5]), __fadd_rn(r[6], r[7])));
}

// kSZ: zero accc/flagCnt; for m<512: sumE_np, embT (f32 transpose for kF),
// split-bf16 codebook ebh/ebl (e = eh + el).
__global__ void kSZ(const float* __restrict__ emb, float* __restrict__ sumE,
                    float* __restrict__ embT, unsigned short* __restrict__ ebh,
                    unsigned short* __restrict__ ebl,
                    float* __restrict__ accc, int* __restrict__ flagCnt) {
    int i = blockIdx.x * 256 + threadIdx.x;
    if (i < M_CODES) accc[i] = 0.f;
    if (i == 0) *flagCnt = 0;
    if (i < M_CODES) {
        sumE[i] = np_pairwise_sumsq128(emb + (size_t)i * D_EMB, 1.0f);
        const float* er = emb + (size_t)i * D_EMB;
        for (int d = 0; d < D_EMB; ++d) {
            float e = er[d];
            embT[d * M_CODES + i] = e;
            unsigned short hh = f2bf(e);
            ebh[i * D_EMB + d] = hh;
            ebl[i * D_EMB + d] = f2bf(e - bf2f(hh));
        }
    }
}

// kA screen via split-bf16 MFMA (16x16x32). (R13-validated.)
__global__ __launch_bounds__(256) void kA(const float* __restrict__ x,
                                          const float* __restrict__ xmask,
                                          const unsigned short* __restrict__ ebh,
                                          const unsigned short* __restrict__ ebl,
                                          const float* __restrict__ sumE,
                                          int* __restrict__ idx_out,
                                          int* __restrict__ flagCnt,
                                          int* __restrict__ flagList,
                                          float* __restrict__ lossW,
                                          float* __restrict__ maskW, int N) {
    __shared__ float xnS[4][16], mkS[4][16];
    int tid = threadIdx.x;
    int wid = tid >> 6, lane = tid & 63;
    int m = lane & 15, kg = lane >> 4;
    int grp = blockIdx.x * 4 + wid;
    int tok0 = grp * 16;
    int tokA = tok0 + m;
    float mk = xmask[tokA];

    bf16x8 ah[4], al[4];
    float xn = 0.f;
#pragma unroll
    for (int ks = 0; ks < 4; ++ks) {
        const float4* p = reinterpret_cast<const float4*>(
            x + (size_t)tokA * D_EMB + ks * 32 + kg * 8);
        float4 v0 = p[0], v1 = p[1];
        float e[8] = {v0.x, v0.y, v0.z, v0.w, v1.x, v1.y, v1.z, v1.w};
        bf16x8 hh, ll;
#pragma unroll
        for (int j = 0; j < 8; ++j) {
            float xv = e[j] * mk;
            xn = fmaf(xv, xv, xn);
            unsigned short h = f2bf(xv);
            hh[j] = (short)h;
            ll[j] = (short)f2bf(xv - bf2f(h));
        }
        ah[ks] = hh;
        al[ks] = ll;
    }
    xn += __shfl_xor(xn, 16, 64);
    xn += __shfl_xor(xn, 32, 64);
    if (kg == 0) { xnS[wid][m] = xn; mkS[wid][m] = mk; }

    float b1[4], b2[4];
    int bi[4];
#pragma unroll
    for (int r = 0; r < 4; ++r) { b1[r] = 3.4e38f; b2[r] = 3.4e38f; bi[r] = 0x7fffffff; }

    for (int ct = 0; ct < 32; ++ct) {
        const bf16x8* bhp = reinterpret_cast<const bf16x8*>(
            ebh + (size_t)(ct * 16 + m) * D_EMB + kg * 8);
        const bf16x8* blp = reinterpret_cast<const bf16x8*>(
            ebl + (size_t)(ct * 16 + m) * D_EMB + kg * 8);
        f32x4 accA = {0.f, 0.f, 0.f, 0.f}, accB = {0.f, 0.f, 0.f, 0.f};
#pragma unroll
        for (int ks = 0; ks < 2; ++ks) {
            bf16x8 bh = bhp[ks * 4], bl = blp[ks * 4];
            accA = __builtin_amdgcn_mfma_f32_16x16x32_bf16(ah[ks], bh, accA, 0, 0, 0);
            accA = __builtin_amdgcn_mfma_f32_16x16x32_bf16(al[ks], bh, accA, 0, 0, 0);
            accA = __builtin_amdgcn_mfma_f32_16x16x32_bf16(ah[ks], bl, accA, 0, 0, 0);
        }
#pragma unroll
        for (int ks = 2; ks < 4; ++ks) {
            bf16x8 bh = bhp[ks * 4], bl = blp[ks * 4];
            accB = __builtin_amdgcn_mfma_f32_16x16x32_bf16(ah[ks], bh, accB, 0, 0, 0);
            accB = __builtin_amdgcn_mfma_f32_16x16x32_bf16(al[ks], bh, accB, 0, 0, 0);
            accB = __builtin_amdgcn_mfma_f32_16x16x32_bf16(ah[ks], bl, accB, 0, 0, 0);
        }
        int c = ct * 16 + m;
        float sE = sumE[c];
#pragma unroll
        for (int r = 0; r < 4; ++r) {
            float s = fmaf(-2.f, accA[r] + accB[r], sE);
            if (s < b1[r]) { b2[r] = b1[r]; b1[r] = s; bi[r] = c; }
            else if (s < b2[r]) b2[r] = s;
        }
    }
#pragma unroll
    for (int off = 1; off <= 8; off <<= 1) {
#pragma unroll
        for (int r = 0; r < 4; ++r) {
            float o1 = __shfl_xor(b1[r], off, 64);
            float o2 = __shfl_xor(b2[r], off, 64);
            int oi = __shfl_xor(bi[r], off, 64);
            if (o1 < b1[r] || (o1 == b1[r] && oi < bi[r])) {
                b2[r] = fminf(b1[r], o2); b1[r] = o1; bi[r] = oi;
            } else {
                b2[r] = fminf(b2[r], o1);
            }
        }
    }
    __syncthreads();
    float liS = 0.f, mkT = 0.f;
#pragma unroll
    for (int r = 0; r < 4; ++r) {
        int row = kg * 4 + r;
        float mkr = mkS[wid][row], xnr = xnS[wid][row];
        liS += mkr * mkr * (xnr + b1[r]);
        mkT += mkr;
        if (m == 0) {
            int tokr = tok0 + row;
            idx_out[tokr] = bi[r];
            if (b2[r] - b1[r] < MARGIN) {
                int pp = atomicAdd(flagCnt, 1);
                flagList[pp] = tokr;
            }
        }
    }
    liS += __shfl_xor(liS, 16, 64);
    liS += __shfl_xor(liS, 32, 64);
    mkT += __shfl_xor(mkT, 16, 64);
    mkT += __shfl_xor(mkT, 32, 64);
    if (lane == 0) { lossW[grp] = liS; maskW[grp] = mkT; }
}

// kF: bit-exact np-f32 rescan for flagged tokens, 4 tokens per wave.
__global__ __launch_bounds__(256) void kF(const float* __restrict__ x,
                                          const float* __restrict__ xmask,
                                          const float* __restrict__ embT,
                                          const float* __restrict__ sumE,
                                          const int* __restrict__ flagCnt,
                                          const int* __restrict__ flagList,
                                          int* __restrict__ idx_out) {
    int wave = (blockIdx.x * 256 + threadIdx.x) >> 6;
    int lane = threadIdx.x & 63;
    int nW = gridDim.x * 4;
    int cnt = *flagCnt;
    for (int j = wave * 4; j < cnt; j += nW * 4) {
        int t[4]; float mk[4], sx[4];
#pragma unroll
        for (int q = 0; q < 4; ++q) {
            int jj = (j + q < cnt) ? (j + q) : j;
            t[q] = flagList[jj];
            mk[q] = xmask[t[q]];
            sx[q] = np_pairwise_sumsq128(x + (size_t)t[q] * D_EMB, mk[q]);
        }
        float acc[4][8];
#pragma unroll
        for (int q = 0; q < 4; ++q)
#pragma unroll
            for (int cb = 0; cb < 8; ++cb) acc[q][cb] = 0.f;
        for (int i = 0; i < D_EMB; ++i) {
            float ev[8];
#pragma unroll
            for (int cb = 0; cb < 8; ++cb) ev[cb] = embT[i * M_CODES + cb * 64 + lane];
            float xq[4];
#pragma unroll
            for (int q = 0; q < 4; ++q) xq[q] = __fmul_rn(x[(size_t)t[q] * D_EMB + i], mk[q]);
#pragma unroll
            for (int q = 0; q < 4; ++q)
#pragma unroll
                for (int cb = 0; cb < 8; ++cb)
                    acc[q][cb] = __fmaf_rn(xq[q], ev[cb], acc[q][cb]);
        }
#pragma unroll
        for (int q = 0; q < 4; ++q) {
            float best = 3.4e38f;
            int bq = 0x7fffffff;
#pragma unroll
            for (int cb = 0; cb < 8; ++cb) {
                int c = cb * 64 + lane;
                float d = __fsub_rn(__fadd_rn(sumE[c], sx[q]), __fmul_rn(2.f, acc[q][cb]));
                if (d < best || (d == best && c < bq)) { best = d; bq = c; }
            }
#pragma unroll
            for (int off = 32; off > 0; off >>= 1) {
                float s2 = __shfl_xor(best, off, 64);
                int i2 = __shfl_xor(bq, off, 64);
                if (s2 < best || (s2 == best && i2 < bq)) { best = s2; bq = i2; }
            }
            if (lane == 0) idx_out[t[q]] = bq;
        }
    }
}

// kScat: LDS-accumulated scatter + fused q_st write. Block = (dim-quarter q,
// token chunk of SCHUNK). accD[512][32] in LDS (code-rotated swizzle for bank
// spread); flush = PLAIN coalesced writes to partialD[bid] (R13: 8.4M global
// f32 atomics = 140 MB HBM RMW; LDS atomics + partials avoid it).
__global__ __launch_bounds__(256) void kScat(const float* __restrict__ x,
                                             const float* __restrict__ emb,
                                             const float* __restrict__ xmask,
                                             const int* __restrict__ idx,
                                             float* __restrict__ q_st,
                                             float* __restrict__ partialD,
                                             float* __restrict__ accc,
                                             int N, int nch) {
    __shared__ float accD[M_CODES * 32];
    __shared__ float accC[M_CODES];
    int bid = blockIdx.x;
    int q = bid / nch, ch = bid - q * nch;
    int tid = threadIdx.x;
    for (int i = tid; i < M_CODES * 32; i += 256) accD[i] = 0.f;
    if (q == 0)
        for (int i = tid; i < M_CODES; i += 256) accC[i] = 0.f;
    __syncthreads();
    int tl = tid >> 2, dl = tid & 3;
    int base = ch * SCHUNK;
    for (int it = 0; it < SCHUNK / 64; ++it) {
        int t = base + it * 64 + tl;
        if (t < N) {
            int id = idx[t];
            float mk = xmask[t];
            const float4* xp = reinterpret_cast<const float4*>(
                x + (size_t)t * D_EMB + q * 32 + dl * 8);
            const float4* ep = reinterpret_cast<const float4*>(
                emb + (size_t)id * D_EMB + q * 32 + dl * 8);
            float4 xv0 = xp[0], xv1 = xp[1];
            float4 ev0 = ep[0], ev1 = ep[1];
            float4 o0, o1;
            o0.x = ev0.x * mk; o0.y = ev0.y * mk; o0.z = ev0.z * mk; o0.w = ev0.w * mk;
            o1.x = ev1.x * mk; o1.y = ev1.y * mk; o1.z = ev1.z * mk; o1.w = ev1.w * mk;
            float4* qp = reinterpret_cast<float4*>(
                q_st + (size_t)t * D_EMB + q * 32 + dl * 8);
            qp[0] = o0; qp[1] = o1;
            float vx[8] = {xv0.x * mk, xv0.y * mk, xv0.z * mk, xv0.w * mk,
                           xv1.x * mk, xv1.y * mk, xv1.z * mk, xv1.w * mk};
            int d0 = dl * 8;
#pragma unroll
            for (int j = 0; j < 8; ++j) {
                int dd = d0 + j;
                atomicAdd(&accD[id * 32 + ((dd + id) & 31)], vx[j]);
            }
            if (q == 0 && dl == 0) atomicAdd(&accC[id], 1.f);
        }
    }
    __syncthreads();
    float* pD = partialD + (size_t)bid * (M_CODES * 32);
    for (int i = tid; i < M_CODES * 32; i += 256) {
        int c = i >> 5, dd = i & 31;
        pD[i] = accD[c * 32 + ((dd + c) & 31)];
    }
    if (q == 0)
        for (int i = tid; i < M_CODES; i += 256) atomicAdd(&accc[i], accC[i]);
}

// kC: count normalization + loss finalize.
__global__ __launch_bounds__(512) void kC(const float* __restrict__ counts,
                                          const float* __restrict__ ema_count,
                                          float* __restrict__ new_count_out,
                                          float* __restrict__ norm_ws,
                                          const float* __restrict__ lossP,
                                          const float* __restrict__ maskP,
                                          float* __restrict__ loss_out, int nP) {
    __shared__ float red[512];
    int t = threadIdx.x;
    float raw = 0.999f * ema_count[t] + 0.001f * counts[t];
    red[t] = raw;
    __syncthreads();
#pragma unroll
    for (int s = 256; s > 0; s >>= 1) {
        if (t < s) red[t] += red[t + s];
        __syncthreads();
    }
    float nsum = red[0];
    __syncthreads();
    float norm = (raw + 1e-5f) / (nsum + (float)M_CODES * 1e-5f) * nsum;
    new_count_out[t] = norm;
    norm_ws[t] = norm;

    float lp = 0.f, mp = 0.f;
    for (int i = t; i < nP; i += 512) { lp += lossP[i]; mp += maskP[i]; }
    red[t] = lp;
    __syncthreads();
#pragma unroll
    for (int s = 256; s > 0; s >>= 1) {
        if (t < s) red[t] += red[t + s];
        __syncthreads();
    }
    float S = red[0];
    __syncthreads();
    red[t] = mp;
    __syncthreads();
#pragma unroll
    for (int s = 256; s > 0; s >>= 1) {
        if (t < s) red[t] += red[t + s];
        __syncthreads();
    }
    if (t == 0) loss_out[0] = 0.25f * S / (red[0] * (float)D_EMB);
}

// kWD2: reduce chunk partials + EMA + divide.
__global__ void kWD2(const float* __restrict__ partialD,
                     const float* __restrict__ ema_w,
                     const float* __restrict__ norm_ws,
                     float* __restrict__ new_w, float* __restrict__ new_emb,
                     int nch) {
    int i = blockIdx.x * 256 + threadIdx.x;   // 65536 elements
    int c = i >> 7, d = i & 127;
    int q = d >> 5, dd = d & 31;
    float s = 0.f;
    for (int ch = 0; ch < nch; ++ch)
        s += partialD[(size_t)(q * nch + ch) * (M_CODES * 32) + c * 32 + dd];
    float w = 0.999f * ema_w[i] + 0.001f * s;
    new_w[i] = w;
    new_emb[i] = w / norm_ws[c];
}

extern "C" void kernel_launch(void* const* d_in, const int* in_sizes, int n_in,
                              void* d_out, int out_size, void* d_ws, size_t ws_size,
                              hipStream_t stream) {
    const float* x = (const float*)d_in[0];
    const float* xmask = (const float*)d_in[1];
    const float* emb = (const float*)d_in[2];
    const float* ema_count = (const float*)d_in[3];
    const float* ema_weight = (const float*)d_in[4];
    int N = in_sizes[0] / D_EMB;

    float* out = (float*)d_out;
    float* q_st = out;
    float* loss = out + (size_t)N * D_EMB;
    float* new_emb = loss + 1;
    float* new_cnt = new_emb + M_CODES * D_EMB;
    float* new_w = new_cnt + M_CODES;

    int nGrp = N / 16;                         // 4096
    int nch = (N + SCHUNK - 1) / SCHUNK;       // 32
    float* fws = (float*)d_ws;
    int* idx = (int*)fws;                      // N
    float* counts = fws + N;                   // 512 (accc)
    float* norm = counts + M_CODES;            // 512
    float* lossP = norm + M_CODES;             // nGrp
    float* maskP = lossP + nGrp;               // nGrp
    float* sumE = maskP + nGrp;                // 512
    int* flagCnt = (int*)(sumE + M_CODES);     // 4
    int* flagList = flagCnt + 4;               // N
    float* embT = (float*)(flagList + N);      // 65536
    unsigned short* ebh = (unsigned short*)(embT + M_CODES * D_EMB);  // 65536 u16
    unsigned short* ebl = ebh + M_CODES * D_EMB;                      // 65536 u16
    float* partialD = (float*)(ebl + M_CODES * D_EMB);  // 4*nch*512*32 floats (8MB)

    hipLaunchKernelGGL(kSZ, dim3(2), dim3(256), 0, stream,
                       emb, sumE, embT, ebh, ebl, counts, flagCnt);
    hipLaunchKernelGGL(kA, dim3(nGrp / 4), dim3(256), 0, stream, x, xmask, ebh,
                       ebl, sumE, idx, flagCnt, flagList, lossP, maskP, N);
    hipLaunchKernelGGL(kF, dim3(512), dim3(256), 0, stream, x, xmask, embT, sumE,
                       flagCnt, flagList, idx);
    hipLaunchKernelGGL(kScat, dim3(4 * nch), dim3(256), 0, stream, x, emb, xmask,
                       idx, q_st, partialD, counts, N, nch);
    hipLaunchKernelGGL(kC, dim3(1), dim3(512), 0, stream, counts, ema_count,
                       new_cnt, norm, lossP, maskP, loss, nGrp);
    hipLaunchKernelGGL(kWD2, dim3(M_CODES * D_EMB / 256), dim3(256), 0, stream,
                       partialD, ema_weight, norm, new_w, new_emb, nch);
}

// Round 16
// 267.502 us; speedup vs baseline: 1.6400x; 1.1982x over previous
//
#include <hip/hip_runtime.h>

#define M_CODES 512
#define D_EMB 128
#define D4 32
#define MARGIN 5e-5f
#define SCHUNK 2048   // tokens per scatter block

typedef short bf16x8 __attribute__((ext_vector_type(8)));
typedef float f32x4 __attribute__((ext_vector_type(4)));

__device__ __forceinline__ unsigned short f2bf(float f) {  // RNE f32->bf16
    unsigned u = __float_as_uint(f);
    u += 0x7fffu + ((u >> 16) & 1u);
    return (unsigned short)(u >> 16);
}
__device__ __forceinline__ float bf2f(unsigned short h) {
    return __uint_as_float(((unsigned)h) << 16);
}

// numpy pairwise sum (n=128): 8 strided accumulators + tree. (R6-validated.)
__device__ __forceinline__ float np_pairwise_sumsq128(const float* __restrict__ a,
                                                      float scale) {
    float r[8];
#pragma unroll
    for (int j = 0; j < 8; ++j) {
        float v = __fmul_rn(a[j], scale);
        r[j] = __fmul_rn(v, v);
    }
    for (int i = 8; i < 128; i += 8) {
#pragma unroll
        for (int j = 0; j < 8; ++j) {
            float v = __fmul_rn(a[i + j], scale);
            r[j] = __fadd_rn(r[j], __fmul_rn(v, v));
        }
    }
    return __fadd_rn(__fadd_rn(__fadd_rn(r[0], r[1]), __fadd_rn(r[2], r[3])),
                     __fadd_rn(__fadd_rn(r[4], r[5]), __fadd_rn(r[6], r[7])));
}

// kSZ: zero accc/flagCnt; for m<512: sumE_np, embT (f32 transpose for kF),
// split-bf16 codebook ebh/ebl (e = eh + el).
__global__ void kSZ(const float* __restrict__ emb, float* __restrict__ sumE,
                    float* __restrict__ embT, unsigned short* __restrict__ ebh,
                    unsigned short* __restrict__ ebl,
                    float* __restrict__ accc, int* __restrict__ flagCnt) {
    int i = blockIdx.x * 256 + threadIdx.x;
    if (i < M_CODES) accc[i] = 0.f;
    if (i == 0) *flagCnt = 0;
    if (i < M_CODES) {
        sumE[i] = np_pairwise_sumsq128(emb + (size_t)i * D_EMB, 1.0f);
        const float* er = emb + (size_t)i * D_EMB;
        for (int d = 0; d < D_EMB; ++d) {
            float e = er[d];
            embT[d * M_CODES + i] = e;
            unsigned short hh = f2bf(e);
            ebh[i * D_EMB + d] = hh;
            ebl[i * D_EMB + d] = f2bf(e - bf2f(hh));
        }
    }
}

// kA screen via split-bf16 MFMA. R15 evolution: 32 tokens/wave (two A-tiles,
// 24 MFMA per 8 e-fragment loads -> 2x arithmetic intensity; R15 counters
// showed L2-BW/latency bound at 16 tokens/wave) + explicit next-ct b-fragment
// prefetch to hide L2 latency under the MFMA block.
__global__ __launch_bounds__(256) void kA(const float* __restrict__ x,
                                          const float* __restrict__ xmask,
                                          const unsigned short* __restrict__ ebh,
                                          const unsigned short* __restrict__ ebl,
                                          const float* __restrict__ sumE,
                                          int* __restrict__ idx_out,
                                          int* __restrict__ flagCnt,
                                          int* __restrict__ flagList,
                                          float* __restrict__ lossW,
                                          float* __restrict__ maskW, int N) {
    __shared__ float xnS[4][32], mkS[4][32];
    int tid = threadIdx.x;
    int wid = tid >> 6, lane = tid & 63;
    int m = lane & 15, kg = lane >> 4;
    int grp = blockIdx.x * 4 + wid;
    int tok0 = grp * 32;

    bf16x8 ah0[4], al0[4], ah1[4], al1[4];
    float xn0 = 0.f, xn1 = 0.f;
    float mk0 = xmask[tok0 + m], mk1 = xmask[tok0 + 16 + m];
#pragma unroll
    for (int ks = 0; ks < 4; ++ks) {
        const float4* p0 = reinterpret_cast<const float4*>(
            x + (size_t)(tok0 + m) * D_EMB + ks * 32 + kg * 8);
        const float4* p1 = reinterpret_cast<const float4*>(
            x + (size_t)(tok0 + 16 + m) * D_EMB + ks * 32 + kg * 8);
        float4 a0 = p0[0], a1 = p0[1], c0 = p1[0], c1 = p1[1];
        float e0[8] = {a0.x, a0.y, a0.z, a0.w, a1.x, a1.y, a1.z, a1.w};
        float e1[8] = {c0.x, c0.y, c0.z, c0.w, c1.x, c1.y, c1.z, c1.w};
        bf16x8 h0, l0, h1, l1;
#pragma unroll
        for (int j = 0; j < 8; ++j) {
            float v0 = e0[j] * mk0;
            xn0 = fmaf(v0, v0, xn0);
            unsigned short hh0 = f2bf(v0);
            h0[j] = (short)hh0;
            l0[j] = (short)f2bf(v0 - bf2f(hh0));
            float v1 = e1[j] * mk1;
            xn1 = fmaf(v1, v1, xn1);
            unsigned short hh1 = f2bf(v1);
            h1[j] = (short)hh1;
            l1[j] = (short)f2bf(v1 - bf2f(hh1));
        }
        ah0[ks] = h0; al0[ks] = l0; ah1[ks] = h1; al1[ks] = l1;
    }
    xn0 += __shfl_xor(xn0, 16, 64);
    xn0 += __shfl_xor(xn0, 32, 64);
    xn1 += __shfl_xor(xn1, 16, 64);
    xn1 += __shfl_xor(xn1, 32, 64);
    if (kg == 0) {
        xnS[wid][m] = xn0; mkS[wid][m] = mk0;
        xnS[wid][16 + m] = xn1; mkS[wid][16 + m] = mk1;
    }

    float b1[2][4], b2[2][4];
    int bi[2][4];
#pragma unroll
    for (int tt = 0; tt < 2; ++tt)
#pragma unroll
        for (int r = 0; r < 4; ++r) {
            b1[tt][r] = 3.4e38f; b2[tt][r] = 3.4e38f; bi[tt][r] = 0x7fffffff;
        }

    const unsigned short* ebhL = ebh + (size_t)m * D_EMB + kg * 8;
    const unsigned short* eblL = ebl + (size_t)m * D_EMB + kg * 8;
    bf16x8 bh[4], bl[4];
#pragma unroll
    for (int ks = 0; ks < 4; ++ks) {
        bh[ks] = *reinterpret_cast<const bf16x8*>(ebhL + ks * 32);
        bl[ks] = *reinterpret_cast<const bf16x8*>(eblL + ks * 32);
    }
    for (int ct = 0; ct < 32; ++ct) {
        // prefetch next ct's fragments (clamped; redundant on last iter)
        int ctn = ct < 31 ? ct + 1 : 31;
        const unsigned short* nbhp = ebhL + (size_t)ctn * 16 * D_EMB;
        const unsigned short* nblp = eblL + (size_t)ctn * 16 * D_EMB;
        bf16x8 nbh[4], nbl[4];
#pragma unroll
        for (int ks = 0; ks < 4; ++ks) {
            nbh[ks] = *reinterpret_cast<const bf16x8*>(nbhp + ks * 32);
            nbl[ks] = *reinterpret_cast<const bf16x8*>(nblp + ks * 32);
        }
        f32x4 accA0 = {0.f, 0.f, 0.f, 0.f}, accB0 = {0.f, 0.f, 0.f, 0.f};
        f32x4 accA1 = {0.f, 0.f, 0.f, 0.f}, accB1 = {0.f, 0.f, 0.f, 0.f};
#pragma unroll
        for (int ks = 0; ks < 2; ++ks) {
            accA0 = __builtin_amdgcn_mfma_f32_16x16x32_bf16(ah0[ks], bh[ks], accA0, 0, 0, 0);
            accA0 = __builtin_amdgcn_mfma_f32_16x16x32_bf16(al0[ks], bh[ks], accA0, 0, 0, 0);
            accA0 = __builtin_amdgcn_mfma_f32_16x16x32_bf16(ah0[ks], bl[ks], accA0, 0, 0, 0);
            accA1 = __builtin_amdgcn_mfma_f32_16x16x32_bf16(ah1[ks], bh[ks], accA1, 0, 0, 0);
            accA1 = __builtin_amdgcn_mfma_f32_16x16x32_bf16(al1[ks], bh[ks], accA1, 0, 0, 0);
            accA1 = __builtin_amdgcn_mfma_f32_16x16x32_bf16(ah1[ks], bl[ks], accA1, 0, 0, 0);
        }
#pragma unroll
        for (int ks = 2; ks < 4; ++ks) {
            accB0 = __builtin_amdgcn_mfma_f32_16x16x32_bf16(ah0[ks], bh[ks], accB0, 0, 0, 0);
            accB0 = __builtin_amdgcn_mfma_f32_16x16x32_bf16(al0[ks], bh[ks], accB0, 0, 0, 0);
            accB0 = __builtin_amdgcn_mfma_f32_16x16x32_bf16(ah0[ks], bl[ks], accB0, 0, 0, 0);
            accB1 = __builtin_amdgcn_mfma_f32_16x16x32_bf16(ah1[ks], bh[ks], accB1, 0, 0, 0);
            accB1 = __builtin_amdgcn_mfma_f32_16x16x32_bf16(al1[ks], bh[ks], accB1, 0, 0, 0);
            accB1 = __builtin_amdgcn_mfma_f32_16x16x32_bf16(ah1[ks], bl[ks], accB1, 0, 0, 0);
        }
        int c = ct * 16 + m;
        float sE = sumE[c];
#pragma unroll
        for (int r = 0; r < 4; ++r) {
            float s0 = fmaf(-2.f, accA0[r] + accB0[r], sE);
            if (s0 < b1[0][r]) { b2[0][r] = b1[0][r]; b1[0][r] = s0; bi[0][r] = c; }
            else if (s0 < b2[0][r]) b2[0][r] = s0;
            float s1 = fmaf(-2.f, accA1[r] + accB1[r], sE);
            if (s1 < b1[1][r]) { b2[1][r] = b1[1][r]; b1[1][r] = s1; bi[1][r] = c; }
            else if (s1 < b2[1][r]) b2[1][r] = s1;
        }
#pragma unroll
        for (int ks = 0; ks < 4; ++ks) { bh[ks] = nbh[ks]; bl[ks] = nbl[ks]; }
    }
    // merge across the 16 col-lanes
#pragma unroll
    for (int off = 1; off <= 8; off <<= 1) {
#pragma unroll
        for (int tt = 0; tt < 2; ++tt)
#pragma unroll
            for (int r = 0; r < 4; ++r) {
                float o1 = __shfl_xor(b1[tt][r], off, 64);
                float o2 = __shfl_xor(b2[tt][r], off, 64);
                int oi = __shfl_xor(bi[tt][r], off, 64);
                if (o1 < b1[tt][r] || (o1 == b1[tt][r] && oi < bi[tt][r])) {
                    b2[tt][r] = fminf(b1[tt][r], o2); b1[tt][r] = o1; bi[tt][r] = oi;
                } else {
                    b2[tt][r] = fminf(b2[tt][r], o1);
                }
            }
    }
    __syncthreads();
    float liS = 0.f, mkT = 0.f;
#pragma unroll
    for (int tt = 0; tt < 2; ++tt)
#pragma unroll
        for (int r = 0; r < 4; ++r) {
            int row = kg * 4 + r;
            float mkr = mkS[wid][tt * 16 + row], xnr = xnS[wid][tt * 16 + row];
            liS += mkr * mkr * (xnr + b1[tt][r]);
            mkT += mkr;
            if (m == 0) {
                int tokr = tok0 + tt * 16 + row;
                idx_out[tokr] = bi[tt][r];
                if (b2[tt][r] - b1[tt][r] < MARGIN) {
                    int pp = atomicAdd(flagCnt, 1);
                    flagList[pp] = tokr;
                }
            }
        }
    liS += __shfl_xor(liS, 16, 64);
    liS += __shfl_xor(liS, 32, 64);
    mkT += __shfl_xor(mkT, 16, 64);
    mkT += __shfl_xor(mkT, 32, 64);
    if (lane == 0) { lossW[grp] = liS; maskW[grp] = mkT; }
}

// kF: bit-exact np-f32 rescan for flagged tokens, 4 tokens per wave.
__global__ __launch_bounds__(256) void kF(const float* __restrict__ x,
                                          const float* __restrict__ xmask,
                                          const float* __restrict__ embT,
                                          const float* __restrict__ sumE,
                                          const int* __restrict__ flagCnt,
                                          const int* __restrict__ flagList,
                                          int* __restrict__ idx_out) {
    int wave = (blockIdx.x * 256 + threadIdx.x) >> 6;
    int lane = threadIdx.x & 63;
    int nW = gridDim.x * 4;
    int cnt = *flagCnt;
    for (int j = wave * 4; j < cnt; j += nW * 4) {
        int t[4]; float mk[4], sx[4];
#pragma unroll
        for (int q = 0; q < 4; ++q) {
            int jj = (j + q < cnt) ? (j + q) : j;
            t[q] = flagList[jj];
            mk[q] = xmask[t[q]];
            sx[q] = np_pairwise_sumsq128(x + (size_t)t[q] * D_EMB, mk[q]);
        }
        float acc[4][8];
#pragma unroll
        for (int q = 0; q < 4; ++q)
#pragma unroll
            for (int cb = 0; cb < 8; ++cb) acc[q][cb] = 0.f;
        for (int i = 0; i < D_EMB; ++i) {
            float ev[8];
#pragma unroll
            for (int cb = 0; cb < 8; ++cb) ev[cb] = embT[i * M_CODES + cb * 64 + lane];
            float xq[4];
#pragma unroll
            for (int q = 0; q < 4; ++q) xq[q] = __fmul_rn(x[(size_t)t[q] * D_EMB + i], mk[q]);
#pragma unroll
            for (int q = 0; q < 4; ++q)
#pragma unroll
                for (int cb = 0; cb < 8; ++cb)
                    acc[q][cb] = __fmaf_rn(xq[q], ev[cb], acc[q][cb]);
        }
#pragma unroll
        for (int q = 0; q < 4; ++q) {
            float best = 3.4e38f;
            int bq = 0x7fffffff;
#pragma unroll
            for (int cb = 0; cb < 8; ++cb) {
                int c = cb * 64 + lane;
                float d = __fsub_rn(__fadd_rn(sumE[c], sx[q]), __fmul_rn(2.f, acc[q][cb]));
                if (d < best || (d == best && c < bq)) { best = d; bq = c; }
            }
#pragma unroll
            for (int off = 32; off > 0; off >>= 1) {
                float s2 = __shfl_xor(best, off, 64);
                int i2 = __shfl_xor(bq, off, 64);
                if (s2 < best || (s2 == best && i2 < bq)) { best = s2; bq = i2; }
            }
            if (lane == 0) idx_out[t[q]] = bq;
        }
    }
}

// kScat: LDS-accumulated scatter + fused q_st write. (R15-validated.)
__global__ __launch_bounds__(256) void kScat(const float* __restrict__ x,
                                             const float* __restrict__ emb,
                                             const float* __restrict__ xmask,
                                             const int* __restrict__ idx,
                                             float* __restrict__ q_st,
                                             float* __restrict__ partialD,
                                             float* __restrict__ accc,
                                             int N, int nch) {
    __shared__ float accD[M_CODES * 32];
    __shared__ float accC[M_CODES];
    int bid = blockIdx.x;
    int q = bid / nch, ch = bid - q * nch;
    int tid = threadIdx.x;
    for (int i = tid; i < M_CODES * 32; i += 256) accD[i] = 0.f;
    if (q == 0)
        for (int i = tid; i < M_CODES; i += 256) accC[i] = 0.f;
    __syncthreads();
    int tl = tid >> 2, dl = tid & 3;
    int base = ch * SCHUNK;
    for (int it = 0; it < SCHUNK / 64; ++it) {
        int t = base + it * 64 + tl;
        if (t < N) {
            int id = idx[t];
            float mk = xmask[t];
            const float4* xp = reinterpret_cast<const float4*>(
                x + (size_t)t * D_EMB + q * 32 + dl * 8);
            const float4* ep = reinterpret_cast<const float4*>(
                emb + (size_t)id * D_EMB + q * 32 + dl * 8);
            float4 xv0 = xp[0], xv1 = xp[1];
            float4 ev0 = ep[0], ev1 = ep[1];
            float4 o0, o1;
            o0.x = ev0.x * mk; o0.y = ev0.y * mk; o0.z = ev0.z * mk; o0.w = ev0.w * mk;
            o1.x = ev1.x * mk; o1.y = ev1.y * mk; o1.z = ev1.z * mk; o1.w = ev1.w * mk;
            float4* qp = reinterpret_cast<float4*>(
                q_st + (size_t)t * D_EMB + q * 32 + dl * 8);
            qp[0] = o0; qp[1] = o1;
            float vx[8] = {xv0.x * mk, xv0.y * mk, xv0.z * mk, xv0.w * mk,
                           xv1.x * mk, xv1.y * mk, xv1.z * mk, xv1.w * mk};
            int d0 = dl * 8;
#pragma unroll
            for (int j = 0; j < 8; ++j) {
                int dd = d0 + j;
                atomicAdd(&accD[id * 32 + ((dd + id) & 31)], vx[j]);
            }
            if (q == 0 && dl == 0) atomicAdd(&accC[id], 1.f);
        }
    }
    __syncthreads();
    float* pD = partialD + (size_t)bid * (M_CODES * 32);
    for (int i = tid; i < M_CODES * 32; i += 256) {
        int c = i >> 5, dd = i & 31;
        pD[i] = accD[c * 32 + ((dd + c) & 31)];
    }
    if (q == 0)
        for (int i = tid; i < M_CODES; i += 256) atomicAdd(&accc[i], accC[i]);
}

// kC: count normalization + loss finalize.
__global__ __launch_bounds__(512) void kC(const float* __restrict__ counts,
                                          const float* __restrict__ ema_count,
                                          float* __restrict__ new_count_out,
                                          float* __restrict__ norm_ws,
                                          const float* __restrict__ lossP,
                                          const float* __restrict__ maskP,
                                          float* __restrict__ loss_out, int nP) {
    __shared__ float red[512];
    int t = threadIdx.x;
    float raw = 0.999f * ema_count[t] + 0.001f * counts[t];
    red[t] = raw;
    __syncthreads();
#pragma unroll
    for (int s = 256; s > 0; s >>= 1) {
        if (t < s) red[t] += red[t + s];
        __syncthreads();
    }
    float nsum = red[0];
    __syncthreads();
    float norm = (raw + 1e-5f) / (nsum + (float)M_CODES * 1e-5f) * nsum;
    new_count_out[t] = norm;
    norm_ws[t] = norm;

    float lp = 0.f, mp = 0.f;
    for (int i = t; i < nP; i += 512) { lp += lossP[i]; mp += maskP[i]; }
    red[t] = lp;
    __syncthreads();
#pragma unroll
    for (int s = 256; s > 0; s >>= 1) {
        if (t < s) red[t] += red[t + s];
        __syncthreads();
    }
    float S = red[0];
    __syncthreads();
    red[t] = mp;
    __syncthreads();
#pragma unroll
    for (int s = 256; s > 0; s >>= 1) {
        if (t < s) red[t] += red[t + s];
        __syncthreads();
    }
    if (t == 0) loss_out[0] = 0.25f * S / (red[0] * (float)D_EMB);
}

// kWD2: reduce chunk partials + EMA + divide.
__global__ void kWD2(const float* __restrict__ partialD,
                     const float* __restrict__ ema_w,
                     const float* __restrict__ norm_ws,
                     float* __restrict__ new_w, float* __restrict__ new_emb,
                     int nch) {
    int i = blockIdx.x * 256 + threadIdx.x;   // 65536 elements
    int c = i >> 7, d = i & 127;
    int q = d >> 5, dd = d & 31;
    float s = 0.f;
    for (int ch = 0; ch < nch; ++ch)
        s += partialD[(size_t)(q * nch + ch) * (M_CODES * 32) + c * 32 + dd];
    float w = 0.999f * ema_w[i] + 0.001f * s;
    new_w[i] = w;
    new_emb[i] = w / norm_ws[c];
}

extern "C" void kernel_launch(void* const* d_in, const int* in_sizes, int n_in,
                              void* d_out, int out_size, void* d_ws, size_t ws_size,
                              hipStream_t stream) {
    const float* x = (const float*)d_in[0];
    const float* xmask = (const float*)d_in[1];
    const float* emb = (const float*)d_in[2];
    const float* ema_count = (const float*)d_in[3];
    const float* ema_weight = (const float*)d_in[4];
    int N = in_sizes[0] / D_EMB;

    float* out = (float*)d_out;
    float* q_st = out;
    float* loss = out + (size_t)N * D_EMB;
    float* new_emb = loss + 1;
    float* new_cnt = new_emb + M_CODES * D_EMB;
    float* new_w = new_cnt + M_CODES;

    int nGrp = N / 32;                         // 2048 (32 tokens per group)
    int nch = (N + SCHUNK - 1) / SCHUNK;       // 32
    float* fws = (float*)d_ws;
    int* idx = (int*)fws;                      // N
    float* counts = fws + N;                   // 512 (accc)
    float* norm = counts + M_CODES;            // 512
    float* lossP = norm + M_CODES;             // nGrp
    float* maskP = lossP + nGrp;               // nGrp
    float* sumE = maskP + nGrp;                // 512
    int* flagCnt = (int*)(sumE + M_CODES);     // 4
    int* flagList = flagCnt + 4;               // N
    float* embT = (float*)(flagList + N);      // 65536
    unsigned short* ebh = (unsigned short*)(embT + M_CODES * D_EMB);  // 65536 u16
    unsigned short* ebl = ebh + M_CODES * D_EMB;                      // 65536 u16
    float* partialD = (float*)(ebl + M_CODES * D_EMB);  // 4*nch*512*32 floats (8MB)

    hipLaunchKernelGGL(kSZ, dim3(2), dim3(256), 0, stream,
                       emb, sumE, embT, ebh, ebl, counts, flagCnt);
    hipLaunchKernelGGL(kA, dim3(nGrp / 4), dim3(256), 0, stream, x, xmask, ebh,
                       ebl, sumE, idx, flagCnt, flagList, lossP, maskP, N);
    hipLaunchKernelGGL(kF, dim3(512), dim3(256), 0, stream, x, xmask, embT, sumE,
                       flagCnt, flagList, idx);
    hipLaunchKernelGGL(kScat, dim3(4 * nch), dim3(256), 0, stream, x, emb, xmask,
                       idx, q_st, partialD, counts, N, nch);
    hipLaunchKernelGGL(kC, dim3(1), dim3(512), 0, stream, counts, ema_count,
                       new_cnt, norm, lossP, maskP, loss, nGrp);
    hipLaunchKernelGGL(kWD2, dim3(M_CODES * D_EMB / 256), dim3(256), 0, stream,
                       partialD, ema_weight, norm, new_w, new_emb, nch);
}

// Round 17
// 231.176 us; speedup vs baseline: 1.8977x; 1.1571x over previous
//
#include <hip/hip_runtime.h>

#define M_CODES 512
#define D_EMB 128
#define D4 32
#define MARGIN 5e-5f
#define SCHUNK 1024   // tokens per scatter chunk

typedef short bf16x8 __attribute__((ext_vector_type(8)));
typedef float f32x4 __attribute__((ext_vector_type(4)));

__device__ __forceinline__ unsigned short f2bf(float f) {  // RNE f32->bf16
    unsigned u = __float_as_uint(f);
    u += 0x7fffu + ((u >> 16) & 1u);
    return (unsigned short)(u >> 16);
}
__device__ __forceinline__ float bf2f(unsigned short h) {
    return __uint_as_float(((unsigned)h) << 16);
}

// numpy pairwise sum (n=128): 8 strided accumulators + tree. (R6-validated.)
__device__ __forceinline__ float np_pairwise_sumsq128(const float* __restrict__ a,
                                                      float scale) {
    float r[8];
#pragma unroll
    for (int j = 0; j < 8; ++j) {
        float v = __fmul_rn(a[j], scale);
        r[j] = __fmul_rn(v, v);
    }
    for (int i = 8; i < 128; i += 8) {
#pragma unroll
        for (int j = 0; j < 8; ++j) {
            float v = __fmul_rn(a[i + j], scale);
            r[j] = __fadd_rn(r[j], __fmul_rn(v, v));
        }
    }
    return __fadd_rn(__fadd_rn(__fadd_rn(r[0], r[1]), __fadd_rn(r[2], r[3])),
                     __fadd_rn(__fadd_rn(r[4], r[5]), __fadd_rn(r[6], r[7])));
}

// kSZ: zero accc/flagCnt; for m<512: sumE_np, embT (f32 transpose for kF),
// split-bf16 codebook ebh/ebl (e = eh + el).
__global__ void kSZ(const float* __restrict__ emb, float* __restrict__ sumE,
                    float* __restrict__ embT, unsigned short* __restrict__ ebh,
                    unsigned short* __restrict__ ebl,
                    float* __restrict__ accc, int* __restrict__ flagCnt) {
    int i = blockIdx.x * 256 + threadIdx.x;
    if (i < M_CODES) accc[i] = 0.f;
    if (i == 0) *flagCnt = 0;
    if (i < M_CODES) {
        sumE[i] = np_pairwise_sumsq128(emb + (size_t)i * D_EMB, 1.0f);
        const float* er = emb + (size_t)i * D_EMB;
        for (int d = 0; d < D_EMB; ++d) {
            float e = er[d];
            embT[d * M_CODES + i] = e;
            unsigned short hh = f2bf(e);
            ebh[i * D_EMB + d] = hh;
            ebl[i * D_EMB + d] = f2bf(e - bf2f(hh));
        }
    }
}

// kA screen via split-bf16 MFMA, 32 tokens/wave + b-fragment prefetch.
// (R16-validated: fell out of top-5.)
__global__ __launch_bounds__(256) void kA(const float* __restrict__ x,
                                          const float* __restrict__ xmask,
                                          const unsigned short* __restrict__ ebh,
                                          const unsigned short* __restrict__ ebl,
                                          const float* __restrict__ sumE,
                                          int* __restrict__ idx_out,
                                          int* __restrict__ flagCnt,
                                          int* __restrict__ flagList,
                                          float* __restrict__ lossW,
                                          float* __restrict__ maskW, int N) {
    __shared__ float xnS[4][32], mkS[4][32];
    int tid = threadIdx.x;
    int wid = tid >> 6, lane = tid & 63;
    int m = lane & 15, kg = lane >> 4;
    int grp = blockIdx.x * 4 + wid;
    int tok0 = grp * 32;

    bf16x8 ah0[4], al0[4], ah1[4], al1[4];
    float xn0 = 0.f, xn1 = 0.f;
    float mk0 = xmask[tok0 + m], mk1 = xmask[tok0 + 16 + m];
#pragma unroll
    for (int ks = 0; ks < 4; ++ks) {
        const float4* p0 = reinterpret_cast<const float4*>(
            x + (size_t)(tok0 + m) * D_EMB + ks * 32 + kg * 8);
        const float4* p1 = reinterpret_cast<const float4*>(
            x + (size_t)(tok0 + 16 + m) * D_EMB + ks * 32 + kg * 8);
        float4 a0 = p0[0], a1 = p0[1], c0 = p1[0], c1 = p1[1];
        float e0[8] = {a0.x, a0.y, a0.z, a0.w, a1.x, a1.y, a1.z, a1.w};
        float e1[8] = {c0.x, c0.y, c0.z, c0.w, c1.x, c1.y, c1.z, c1.w};
        bf16x8 h0, l0, h1, l1;
#pragma unroll
        for (int j = 0; j < 8; ++j) {
            float v0 = e0[j] * mk0;
            xn0 = fmaf(v0, v0, xn0);
            unsigned short hh0 = f2bf(v0);
            h0[j] = (short)hh0;
            l0[j] = (short)f2bf(v0 - bf2f(hh0));
            float v1 = e1[j] * mk1;
            xn1 = fmaf(v1, v1, xn1);
            unsigned short hh1 = f2bf(v1);
            h1[j] = (short)hh1;
            l1[j] = (short)f2bf(v1 - bf2f(hh1));
        }
        ah0[ks] = h0; al0[ks] = l0; ah1[ks] = h1; al1[ks] = l1;
    }
    xn0 += __shfl_xor(xn0, 16, 64);
    xn0 += __shfl_xor(xn0, 32, 64);
    xn1 += __shfl_xor(xn1, 16, 64);
    xn1 += __shfl_xor(xn1, 32, 64);
    if (kg == 0) {
        xnS[wid][m] = xn0; mkS[wid][m] = mk0;
        xnS[wid][16 + m] = xn1; mkS[wid][16 + m] = mk1;
    }

    float b1[2][4], b2[2][4];
    int bi[2][4];
#pragma unroll
    for (int tt = 0; tt < 2; ++tt)
#pragma unroll
        for (int r = 0; r < 4; ++r) {
            b1[tt][r] = 3.4e38f; b2[tt][r] = 3.4e38f; bi[tt][r] = 0x7fffffff;
        }

    const unsigned short* ebhL = ebh + (size_t)m * D_EMB + kg * 8;
    const unsigned short* eblL = ebl + (size_t)m * D_EMB + kg * 8;
    bf16x8 bh[4], bl[4];
#pragma unroll
    for (int ks = 0; ks < 4; ++ks) {
        bh[ks] = *reinterpret_cast<const bf16x8*>(ebhL + ks * 32);
        bl[ks] = *reinterpret_cast<const bf16x8*>(eblL + ks * 32);
    }
    for (int ct = 0; ct < 32; ++ct) {
        int ctn = ct < 31 ? ct + 1 : 31;
        const unsigned short* nbhp = ebhL + (size_t)ctn * 16 * D_EMB;
        const unsigned short* nblp = eblL + (size_t)ctn * 16 * D_EMB;
        bf16x8 nbh[4], nbl[4];
#pragma unroll
        for (int ks = 0; ks < 4; ++ks) {
            nbh[ks] = *reinterpret_cast<const bf16x8*>(nbhp + ks * 32);
            nbl[ks] = *reinterpret_cast<const bf16x8*>(nblp + ks * 32);
        }
        f32x4 accA0 = {0.f, 0.f, 0.f, 0.f}, accB0 = {0.f, 0.f, 0.f, 0.f};
        f32x4 accA1 = {0.f, 0.f, 0.f, 0.f}, accB1 = {0.f, 0.f, 0.f, 0.f};
#pragma unroll
        for (int ks = 0; ks < 2; ++ks) {
            accA0 = __builtin_amdgcn_mfma_f32_16x16x32_bf16(ah0[ks], bh[ks], accA0, 0, 0, 0);
            accA0 = __builtin_amdgcn_mfma_f32_16x16x32_bf16(al0[ks], bh[ks], accA0, 0, 0, 0);
            accA0 = __builtin_amdgcn_mfma_f32_16x16x32_bf16(ah0[ks], bl[ks], accA0, 0, 0, 0);
            accA1 = __builtin_amdgcn_mfma_f32_16x16x32_bf16(ah1[ks], bh[ks], accA1, 0, 0, 0);
            accA1 = __builtin_amdgcn_mfma_f32_16x16x32_bf16(al1[ks], bh[ks], accA1, 0, 0, 0);
            accA1 = __builtin_amdgcn_mfma_f32_16x16x32_bf16(ah1[ks], bl[ks], accA1, 0, 0, 0);
        }
#pragma unroll
        for (int ks = 2; ks < 4; ++ks) {
            accB0 = __builtin_amdgcn_mfma_f32_16x16x32_bf16(ah0[ks], bh[ks], accB0, 0, 0, 0);
            accB0 = __builtin_amdgcn_mfma_f32_16x16x32_bf16(al0[ks], bh[ks], accB0, 0, 0, 0);
            accB0 = __builtin_amdgcn_mfma_f32_16x16x32_bf16(ah0[ks], bl[ks], accB0, 0, 0, 0);
            accB1 = __builtin_amdgcn_mfma_f32_16x16x32_bf16(ah1[ks], bh[ks], accB1, 0, 0, 0);
            accB1 = __builtin_amdgcn_mfma_f32_16x16x32_bf16(al1[ks], bh[ks], accB1, 0, 0, 0);
            accB1 = __builtin_amdgcn_mfma_f32_16x16x32_bf16(ah1[ks], bl[ks], accB1, 0, 0, 0);
        }
        int c = ct * 16 + m;
        float sE = sumE[c];
#pragma unroll
        for (int r = 0; r < 4; ++r) {
            float s0 = fmaf(-2.f, accA0[r] + accB0[r], sE);
            if (s0 < b1[0][r]) { b2[0][r] = b1[0][r]; b1[0][r] = s0; bi[0][r] = c; }
            else if (s0 < b2[0][r]) b2[0][r] = s0;
            float s1 = fmaf(-2.f, accA1[r] + accB1[r], sE);
            if (s1 < b1[1][r]) { b2[1][r] = b1[1][r]; b1[1][r] = s1; bi[1][r] = c; }
            else if (s1 < b2[1][r]) b2[1][r] = s1;
        }
#pragma unroll
        for (int ks = 0; ks < 4; ++ks) { bh[ks] = nbh[ks]; bl[ks] = nbl[ks]; }
    }
#pragma unroll
    for (int off = 1; off <= 8; off <<= 1) {
#pragma unroll
        for (int tt = 0; tt < 2; ++tt)
#pragma unroll
            for (int r = 0; r < 4; ++r) {
                float o1 = __shfl_xor(b1[tt][r], off, 64);
                float o2 = __shfl_xor(b2[tt][r], off, 64);
                int oi = __shfl_xor(bi[tt][r], off, 64);
                if (o1 < b1[tt][r] || (o1 == b1[tt][r] && oi < bi[tt][r])) {
                    b2[tt][r] = fminf(b1[tt][r], o2); b1[tt][r] = o1; bi[tt][r] = oi;
                } else {
                    b2[tt][r] = fminf(b2[tt][r], o1);
                }
            }
    }
    __syncthreads();
    float liS = 0.f, mkT = 0.f;
#pragma unroll
    for (int tt = 0; tt < 2; ++tt)
#pragma unroll
        for (int r = 0; r < 4; ++r) {
            int row = kg * 4 + r;
            float mkr = mkS[wid][tt * 16 + row], xnr = xnS[wid][tt * 16 + row];
            liS += mkr * mkr * (xnr + b1[tt][r]);
            mkT += mkr;
            if (m == 0) {
                int tokr = tok0 + tt * 16 + row;
                idx_out[tokr] = bi[tt][r];
                if (b2[tt][r] - b1[tt][r] < MARGIN) {
                    int pp = atomicAdd(flagCnt, 1);
                    flagList[pp] = tokr;
                }
            }
        }
    liS += __shfl_xor(liS, 16, 64);
    liS += __shfl_xor(liS, 32, 64);
    mkT += __shfl_xor(mkT, 16, 64);
    mkT += __shfl_xor(mkT, 32, 64);
    if (lane == 0) { lossW[grp] = liS; maskW[grp] = mkT; }
}

// kF: bit-exact np-f32 rescan for flagged tokens, 4 tokens per wave.
__global__ __launch_bounds__(256) void kF(const float* __restrict__ x,
                                          const float* __restrict__ xmask,
                                          const float* __restrict__ embT,
                                          const float* __restrict__ sumE,
                                          const int* __restrict__ flagCnt,
                                          const int* __restrict__ flagList,
                                          int* __restrict__ idx_out) {
    int wave = (blockIdx.x * 256 + threadIdx.x) >> 6;
    int lane = threadIdx.x & 63;
    int nW = gridDim.x * 4;
    int cnt = *flagCnt;
    for (int j = wave * 4; j < cnt; j += nW * 4) {
        int t[4]; float mk[4], sx[4];
#pragma unroll
        for (int q = 0; q < 4; ++q) {
            int jj = (j + q < cnt) ? (j + q) : j;
            t[q] = flagList[jj];
            mk[q] = xmask[t[q]];
            sx[q] = np_pairwise_sumsq128(x + (size_t)t[q] * D_EMB, mk[q]);
        }
        float acc[4][8];
#pragma unroll
        for (int q = 0; q < 4; ++q)
#pragma unroll
            for (int cb = 0; cb < 8; ++cb) acc[q][cb] = 0.f;
        for (int i = 0; i < D_EMB; ++i) {
            float ev[8];
#pragma unroll
            for (int cb = 0; cb < 8; ++cb) ev[cb] = embT[i * M_CODES + cb * 64 + lane];
            float xq[4];
#pragma unroll
            for (int q = 0; q < 4; ++q) xq[q] = __fmul_rn(x[(size_t)t[q] * D_EMB + i], mk[q]);
#pragma unroll
            for (int q = 0; q < 4; ++q)
#pragma unroll
                for (int cb = 0; cb < 8; ++cb)
                    acc[q][cb] = __fmaf_rn(xq[q], ev[cb], acc[q][cb]);
        }
#pragma unroll
        for (int q = 0; q < 4; ++q) {
            float best = 3.4e38f;
            int bq = 0x7fffffff;
#pragma unroll
            for (int cb = 0; cb < 8; ++cb) {
                int c = cb * 64 + lane;
                float d = __fsub_rn(__fadd_rn(sumE[c], sx[q]), __fmul_rn(2.f, acc[q][cb]));
                if (d < best || (d == best && c < bq)) { best = d; bq = c; }
            }
#pragma unroll
            for (int off = 32; off > 0; off >>= 1) {
                float s2 = __shfl_xor(best, off, 64);
                int i2 = __shfl_xor(bq, off, 64);
                if (s2 < best || (s2 == best && i2 < bq)) { best = s2; bq = i2; }
            }
            if (lane == 0) idx_out[t[q]] = bq;
        }
    }
}

// kScat: LDS-accumulated scatter + fused q_st write. R16 fix: 8 dim-slices of
// 16 (accD [16][512] = 32 KB -> 4 blocks/CU) x 64 token chunks -> grid 512 on
// all 256 CUs (R16: grid 128 = half chip idle, 95 us at 190 GB/s). All 8
// slices of a chunk share an XCD (bid%8 = ch%8, nch%8==0) -> x rows fetched
// once per L2.
__global__ __launch_bounds__(256) void kScat(const float* __restrict__ x,
                                             const float* __restrict__ emb,
                                             const float* __restrict__ xmask,
                                             const int* __restrict__ idx,
                                             float* __restrict__ q_st,
                                             float* __restrict__ partialD,
                                             float* __restrict__ accc,
                                             int N, int nch) {
    __shared__ float accD[16 * M_CODES];   // [dd][code]
    __shared__ float accC[M_CODES];
    int bid = blockIdx.x;
    int q = bid / nch, ch = bid - q * nch;   // q = dim-slice 0..7
    int tid = threadIdx.x;
    for (int i = tid; i < 16 * M_CODES; i += 256) accD[i] = 0.f;
    if (q == 0)
        for (int i = tid; i < M_CODES; i += 256) accC[i] = 0.f;
    __syncthreads();
    int tl = tid >> 1, dl = tid & 1;
    int base = ch * SCHUNK;
    for (int it = 0; it < SCHUNK / 128; ++it) {
        int t = base + it * 128 + tl;
        if (t < N) {
            int id = idx[t];
            float mk = xmask[t];
            const float4* xp = reinterpret_cast<const float4*>(
                x + (size_t)t * D_EMB + q * 16 + dl * 8);
            const float4* ep = reinterpret_cast<const float4*>(
                emb + (size_t)id * D_EMB + q * 16 + dl * 8);
            float4 xv0 = xp[0], xv1 = xp[1];
            float4 ev0 = ep[0], ev1 = ep[1];
            float4 o0, o1;
            o0.x = ev0.x * mk; o0.y = ev0.y * mk; o0.z = ev0.z * mk; o0.w = ev0.w * mk;
            o1.x = ev1.x * mk; o1.y = ev1.y * mk; o1.z = ev1.z * mk; o1.w = ev1.w * mk;
            float4* qp = reinterpret_cast<float4*>(
                q_st + (size_t)t * D_EMB + q * 16 + dl * 8);
            qp[0] = o0; qp[1] = o1;
            float vx[8] = {xv0.x * mk, xv0.y * mk, xv0.z * mk, xv0.w * mk,
                           xv1.x * mk, xv1.y * mk, xv1.z * mk, xv1.w * mk};
            int d0 = dl * 8;
#pragma unroll
            for (int j = 0; j < 8; ++j)
                atomicAdd(&accD[(d0 + j) * M_CODES + id], vx[j]);
            if (q == 0 && dl == 0) atomicAdd(&accC[id], 1.f);
        }
    }
    __syncthreads();
    float* pD = partialD + (size_t)bid * (16 * M_CODES);
    for (int i = tid; i < 16 * M_CODES; i += 256) pD[i] = accD[i];
    if (q == 0)
        for (int i = tid; i < M_CODES; i += 256) atomicAdd(&accc[i], accC[i]);
}

// kC: count normalization + loss finalize.
__global__ __launch_bounds__(512) void kC(const float* __restrict__ counts,
                                          const float* __restrict__ ema_count,
                                          float* __restrict__ new_count_out,
                                          float* __restrict__ norm_ws,
                                          const float* __restrict__ lossP,
                                          const float* __restrict__ maskP,
                                          float* __restrict__ loss_out, int nP) {
    __shared__ float red[512];
    int t = threadIdx.x;
    float raw = 0.999f * ema_count[t] + 0.001f * counts[t];
    red[t] = raw;
    __syncthreads();
#pragma unroll
    for (int s = 256; s > 0; s >>= 1) {
        if (t < s) red[t] += red[t + s];
        __syncthreads();
    }
    float nsum = red[0];
    __syncthreads();
    float norm = (raw + 1e-5f) / (nsum + (float)M_CODES * 1e-5f) * nsum;
    new_count_out[t] = norm;
    norm_ws[t] = norm;

    float lp = 0.f, mp = 0.f;
    for (int i = t; i < nP; i += 512) { lp += lossP[i]; mp += maskP[i]; }
    red[t] = lp;
    __syncthreads();
#pragma unroll
    for (int s = 256; s > 0; s >>= 1) {
        if (t < s) red[t] += red[t + s];
        __syncthreads();
    }
    float S = red[0];
    __syncthreads();
    red[t] = mp;
    __syncthreads();
#pragma unroll
    for (int s = 256; s > 0; s >>= 1) {
        if (t < s) red[t] += red[t + s];
        __syncthreads();
    }
    if (t == 0) loss_out[0] = 0.25f * S / (red[0] * (float)D_EMB);
}

// kWD2: reduce chunk partials + EMA + divide. Thread maps code-fastest so the
// per-ch partial reads are coalesced (fixed d, consecutive c -> consecutive).
__global__ void kWD2(const float* __restrict__ partialD,
                     const float* __restrict__ ema_w,
                     const float* __restrict__ norm_ws,
                     float* __restrict__ new_w, float* __restrict__ new_emb,
                     int nch) {
    int i = blockIdx.x * 256 + threadIdx.x;   // 65536 elements
    int c = i & 511;          // code (fastest)
    int d = i >> 9;           // dim 0..127
    int q = d >> 4, dd = d & 15;
    float s = 0.f;
    for (int ch = 0; ch < nch; ++ch)
        s += partialD[(size_t)(q * nch + ch) * (16 * M_CODES) + dd * M_CODES + c];
    size_t o = (size_t)c * D_EMB + d;
    float w = 0.999f * ema_w[o] + 0.001f * s;
    new_w[o] = w;
    new_emb[o] = w / norm_ws[c];
}

extern "C" void kernel_launch(void* const* d_in, const int* in_sizes, int n_in,
                              void* d_out, int out_size, void* d_ws, size_t ws_size,
                              hipStream_t stream) {
    const float* x = (const float*)d_in[0];
    const float* xmask = (const float*)d_in[1];
    const float* emb = (const float*)d_in[2];
    const float* ema_count = (const float*)d_in[3];
    const float* ema_weight = (const float*)d_in[4];
    int N = in_sizes[0] / D_EMB;

    float* out = (float*)d_out;
    float* q_st = out;
    float* loss = out + (size_t)N * D_EMB;
    float* new_emb = loss + 1;
    float* new_cnt = new_emb + M_CODES * D_EMB;
    float* new_w = new_cnt + M_CODES;

    int nGrp = N / 32;                         // 2048 (32 tokens per group)
    int nch = (N + SCHUNK - 1) / SCHUNK;       // 64
    float* fws = (float*)d_ws;
    int* idx = (int*)fws;                      // N
    float* counts = fws + N;                   // 512 (accc)
    float* norm = counts + M_CODES;            // 512
    float* lossP = norm + M_CODES;             // nGrp
    float* maskP = lossP + nGrp;               // nGrp
    float* sumE = maskP + nGrp;                // 512
    int* flagCnt = (int*)(sumE + M_CODES);     // 4
    int* flagList = flagCnt + 4;               // N
    float* embT = (float*)(flagList + N);      // 65536
    unsigned short* ebh = (unsigned short*)(embT + M_CODES * D_EMB);  // 65536 u16
    unsigned short* ebl = ebh + M_CODES * D_EMB;                      // 65536 u16
    float* partialD = (float*)(ebl + M_CODES * D_EMB);  // 8*nch*16*512 f32 (16MB)

    hipLaunchKernelGGL(kSZ, dim3(2), dim3(256), 0, stream,
                       emb, sumE, embT, ebh, ebl, counts, flagCnt);
    hipLaunchKernelGGL(kA, dim3(nGrp / 4), dim3(256), 0, stream, x, xmask, ebh,
                       ebl, sumE, idx, flagCnt, flagList, lossP, maskP, N);
    hipLaunchKernelGGL(kF, dim3(512), dim3(256), 0, stream, x, xmask, embT, sumE,
                       flagCnt, flagList, idx);
    hipLaunchKernelGGL(kScat, dim3(8 * nch), dim3(256), 0, stream, x, emb, xmask,
                       idx, q_st, partialD, counts, N, nch);
    hipLaunchKernelGGL(kC, dim3(1), dim3(512), 0, stream, counts, ema_count,
                       new_cnt, norm, lossP, maskP, loss, nGrp);
    hipLaunchKernelGGL(kWD2, dim3(M_CODES * D_EMB / 256), dim3(256), 0, stream,
                       partialD, ema_weight, norm, new_w, new_emb, nch);
}

// Round 18
// 224.899 us; speedup vs baseline: 1.9506x; 1.0279x over previous
//
#include <hip/hip_runtime.h>

#define M_CODES 512
#define D_EMB 128
#define D4 32
#define MARGIN 5e-5f
#define SCHUNK 1024   // tokens per scatter chunk

typedef short bf16x8 __attribute__((ext_vector_type(8)));
typedef float f32x4 __attribute__((ext_vector_type(4)));

__device__ __forceinline__ unsigned short f2bf(float f) {  // RNE f32->bf16
    unsigned u = __float_as_uint(f);
    u += 0x7fffu + ((u >> 16) & 1u);
    return (unsigned short)(u >> 16);
}
__device__ __forceinline__ float bf2f(unsigned short h) {
    return __uint_as_float(((unsigned)h) << 16);
}

// numpy pairwise sum (n=128): 8 strided accumulators + tree. (R6-validated.)
__device__ __forceinline__ float np_pairwise_sumsq128(const float* __restrict__ a,
                                                      float scale) {
    float r[8];
#pragma unroll
    for (int j = 0; j < 8; ++j) {
        float v = __fmul_rn(a[j], scale);
        r[j] = __fmul_rn(v, v);
    }
    for (int i = 8; i < 128; i += 8) {
#pragma unroll
        for (int j = 0; j < 8; ++j) {
            float v = __fmul_rn(a[i + j], scale);
            r[j] = __fadd_rn(r[j], __fmul_rn(v, v));
        }
    }
    return __fadd_rn(__fadd_rn(__fadd_rn(r[0], r[1]), __fadd_rn(r[2], r[3])),
                     __fadd_rn(__fadd_rn(r[4], r[5]), __fadd_rn(r[6], r[7])));
}

// kSZ: parallel setup (R17: old version was a 2-block serial launch).
// Grid 128x256: wave per code. Lanes 0..7 replicate the np pairwise-8 pattern
// exactly (16 sequential adds each), then a shuffle tree in the exact
// ((r0+r1)+(r2+r3))+((r4+r5)+(r6+r7)) order -> bit-identical sumE.
__global__ __launch_bounds__(256) void kSZ(const float* __restrict__ emb,
                                           float* __restrict__ sumE,
                                           float* __restrict__ embT,
                                           unsigned short* __restrict__ ebh,
                                           unsigned short* __restrict__ ebl,
                                           float* __restrict__ accc,
                                           int* __restrict__ flagCnt) {
    int tid = threadIdx.x, wid = tid >> 6, lane = tid & 63;
    int m = blockIdx.x * 4 + wid;            // 0..511
    int gi = blockIdx.x * 256 + tid;
    if (gi < M_CODES) accc[gi] = 0.f;
    if (gi == 0) *flagCnt = 0;
    const float* er = emb + (size_t)m * D_EMB;
    float r = 0.f;
    if (lane < 8) {
        float v = __fmul_rn(er[lane], 1.0f);
        r = __fmul_rn(v, v);
        for (int i = 1; i < 16; ++i) {
            float w = __fmul_rn(er[8 * i + lane], 1.0f);
            r = __fadd_rn(r, __fmul_rn(w, w));
        }
    }
    float s1 = __fadd_rn(r, __shfl_xor(r, 1, 64));
    float s2 = __fadd_rn(s1, __shfl_xor(s1, 2, 64));
    float s3 = __fadd_rn(s2, __shfl_xor(s2, 4, 64));
    if (lane == 0) sumE[m] = s3;
#pragma unroll
    for (int dd = lane; dd < D_EMB; dd += 64) {
        float e = er[dd];
        embT[dd * M_CODES + m] = e;
        unsigned short hh = f2bf(e);
        ebh[(size_t)m * D_EMB + dd] = hh;
        ebl[(size_t)m * D_EMB + dd] = f2bf(e - bf2f(hh));
    }
}

// kA screen via split-bf16 MFMA. R17 evolution: 2-way CODE SPLIT -> 4096
// waves = 1024 blocks = 4 blocks/CU = 4 waves/SIMD (the VGPR-104 cap; R17
// had 2 waves/SIMD -> exposed L2 latency, 77 us at MfmaUtil 12.7%).
// Wave = (grp, sub): 32 tokens x codes [sub*256, sub*256+256).
// Partials pb1/pb2/pidx merged by kA2.
__global__ __launch_bounds__(256) void kA(const float* __restrict__ x,
                                          const float* __restrict__ xmask,
                                          const unsigned short* __restrict__ ebh,
                                          const unsigned short* __restrict__ ebl,
                                          const float* __restrict__ sumE,
                                          float* __restrict__ pb1,
                                          float* __restrict__ pb2,
                                          int* __restrict__ pidx,
                                          float* __restrict__ xnrm, int N) {
    int tid = threadIdx.x;
    int wid = tid >> 6, lane = tid & 63;
    int m = lane & 15, kg = lane >> 4;
    int gw = blockIdx.x * 4 + wid;
    int grp = gw >> 1, sub = gw & 1;
    int tok0 = grp * 32;

    bf16x8 ah0[4], al0[4], ah1[4], al1[4];
    float xn0 = 0.f, xn1 = 0.f;
    float mk0 = xmask[tok0 + m], mk1 = xmask[tok0 + 16 + m];
#pragma unroll
    for (int ks = 0; ks < 4; ++ks) {
        const float4* p0 = reinterpret_cast<const float4*>(
            x + (size_t)(tok0 + m) * D_EMB + ks * 32 + kg * 8);
        const float4* p1 = reinterpret_cast<const float4*>(
            x + (size_t)(tok0 + 16 + m) * D_EMB + ks * 32 + kg * 8);
        float4 a0 = p0[0], a1 = p0[1], c0 = p1[0], c1 = p1[1];
        float e0[8] = {a0.x, a0.y, a0.z, a0.w, a1.x, a1.y, a1.z, a1.w};
        float e1[8] = {c0.x, c0.y, c0.z, c0.w, c1.x, c1.y, c1.z, c1.w};
        bf16x8 h0, l0, h1, l1;
#pragma unroll
        for (int j = 0; j < 8; ++j) {
            float v0 = e0[j] * mk0;
            xn0 = fmaf(v0, v0, xn0);
            unsigned short hh0 = f2bf(v0);
            h0[j] = (short)hh0;
            l0[j] = (short)f2bf(v0 - bf2f(hh0));
            float v1 = e1[j] * mk1;
            xn1 = fmaf(v1, v1, xn1);
            unsigned short hh1 = f2bf(v1);
            h1[j] = (short)hh1;
            l1[j] = (short)f2bf(v1 - bf2f(hh1));
        }
        ah0[ks] = h0; al0[ks] = l0; ah1[ks] = h1; al1[ks] = l1;
    }
    xn0 += __shfl_xor(xn0, 16, 64);
    xn0 += __shfl_xor(xn0, 32, 64);
    xn1 += __shfl_xor(xn1, 16, 64);
    xn1 += __shfl_xor(xn1, 32, 64);
    if (sub == 0 && kg == 0) {
        xnrm[tok0 + m] = xn0;
        xnrm[tok0 + 16 + m] = xn1;
    }

    float b1[2][4], b2[2][4];
    int bi[2][4];
#pragma unroll
    for (int tt = 0; tt < 2; ++tt)
#pragma unroll
        for (int r = 0; r < 4; ++r) {
            b1[tt][r] = 3.4e38f; b2[tt][r] = 3.4e38f; bi[tt][r] = 0x7fffffff;
        }

    const unsigned short* ebhL = ebh + (size_t)m * D_EMB + kg * 8;
    const unsigned short* eblL = ebl + (size_t)m * D_EMB + kg * 8;
    int ct0 = sub * 16, ct1 = ct0 + 16;
    bf16x8 bh[4], bl[4];
#pragma unroll
    for (int ks = 0; ks < 4; ++ks) {
        bh[ks] = *reinterpret_cast<const bf16x8*>(ebhL + (size_t)ct0 * 16 * D_EMB + ks * 32);
        bl[ks] = *reinterpret_cast<const bf16x8*>(eblL + (size_t)ct0 * 16 * D_EMB + ks * 32);
    }
    for (int ct = ct0; ct < ct1; ++ct) {
        int ctn = ct < ct1 - 1 ? ct + 1 : ct;
        const unsigned short* nbhp = ebhL + (size_t)ctn * 16 * D_EMB;
        const unsigned short* nblp = eblL + (size_t)ctn * 16 * D_EMB;
        bf16x8 nbh[4], nbl[4];
#pragma unroll
        for (int ks = 0; ks < 4; ++ks) {
            nbh[ks] = *reinterpret_cast<const bf16x8*>(nbhp + ks * 32);
            nbl[ks] = *reinterpret_cast<const bf16x8*>(nblp + ks * 32);
        }
        f32x4 accA0 = {0.f, 0.f, 0.f, 0.f}, accB0 = {0.f, 0.f, 0.f, 0.f};
        f32x4 accA1 = {0.f, 0.f, 0.f, 0.f}, accB1 = {0.f, 0.f, 0.f, 0.f};
#pragma unroll
        for (int ks = 0; ks < 2; ++ks) {
            accA0 = __builtin_amdgcn_mfma_f32_16x16x32_bf16(ah0[ks], bh[ks], accA0, 0, 0, 0);
            accA0 = __builtin_amdgcn_mfma_f32_16x16x32_bf16(al0[ks], bh[ks], accA0, 0, 0, 0);
            accA0 = __builtin_amdgcn_mfma_f32_16x16x32_bf16(ah0[ks], bl[ks], accA0, 0, 0, 0);
            accA1 = __builtin_amdgcn_mfma_f32_16x16x32_bf16(ah1[ks], bh[ks], accA1, 0, 0, 0);
            accA1 = __builtin_amdgcn_mfma_f32_16x16x32_bf16(al1[ks], bh[ks], accA1, 0, 0, 0);
            accA1 = __builtin_amdgcn_mfma_f32_16x16x32_bf16(ah1[ks], bl[ks], accA1, 0, 0, 0);
        }
#pragma unroll
        for (int ks = 2; ks < 4; ++ks) {
            accB0 = __builtin_amdgcn_mfma_f32_16x16x32_bf16(ah0[ks], bh[ks], accB0, 0, 0, 0);
            accB0 = __builtin_amdgcn_mfma_f32_16x16x32_bf16(al0[ks], bh[ks], accB0, 0, 0, 0);
            accB0 = __builtin_amdgcn_mfma_f32_16x16x32_bf16(ah0[ks], bl[ks], accB0, 0, 0, 0);
            accB1 = __builtin_amdgcn_mfma_f32_16x16x32_bf16(ah1[ks], bh[ks], accB1, 0, 0, 0);
            accB1 = __builtin_amdgcn_mfma_f32_16x16x32_bf16(al1[ks], bh[ks], accB1, 0, 0, 0);
            accB1 = __builtin_amdgcn_mfma_f32_16x16x32_bf16(ah1[ks], bl[ks], accB1, 0, 0, 0);
        }
        int c = ct * 16 + m;
        float sE = sumE[c];
#pragma unroll
        for (int r = 0; r < 4; ++r) {
            float s0 = fmaf(-2.f, accA0[r] + accB0[r], sE);
            if (s0 < b1[0][r]) { b2[0][r] = b1[0][r]; b1[0][r] = s0; bi[0][r] = c; }
            else if (s0 < b2[0][r]) b2[0][r] = s0;
            float s1 = fmaf(-2.f, accA1[r] + accB1[r], sE);
            if (s1 < b1[1][r]) { b2[1][r] = b1[1][r]; b1[1][r] = s1; bi[1][r] = c; }
            else if (s1 < b2[1][r]) b2[1][r] = s1;
        }
#pragma unroll
        for (int ks = 0; ks < 4; ++ks) { bh[ks] = nbh[ks]; bl[ks] = nbl[ks]; }
    }
    // merge across the 16 col-lanes (codes)
#pragma unroll
    for (int off = 1; off <= 8; off <<= 1) {
#pragma unroll
        for (int tt = 0; tt < 2; ++tt)
#pragma unroll
            for (int r = 0; r < 4; ++r) {
                float o1 = __shfl_xor(b1[tt][r], off, 64);
                float o2 = __shfl_xor(b2[tt][r], off, 64);
                int oi = __shfl_xor(bi[tt][r], off, 64);
                if (o1 < b1[tt][r] || (o1 == b1[tt][r] && oi < bi[tt][r])) {
                    b2[tt][r] = fminf(b1[tt][r], o2); b1[tt][r] = o1; bi[tt][r] = oi;
                } else {
                    b2[tt][r] = fminf(b2[tt][r], o1);
                }
            }
    }
    if (m == 0) {
#pragma unroll
        for (int tt = 0; tt < 2; ++tt)
#pragma unroll
            for (int r = 0; r < 4; ++r) {
                size_t o = (size_t)sub * N + tok0 + tt * 16 + kg * 4 + r;
                pb1[o] = b1[tt][r];
                pb2[o] = b2[tt][r];
                pidx[o] = bi[tt][r];
            }
    }
}

// kA2: merge the 2 code-subset partials -> idx, near-tie flags, loss/mask
// block partials. (R7-validated merge semantics; ties -> gap 0 -> flagged.)
__global__ __launch_bounds__(256) void kA2(const float* __restrict__ pb1,
                                           const float* __restrict__ pb2,
                                           const int* __restrict__ pidx,
                                           const float* __restrict__ xnrm,
                                           const float* __restrict__ xmask,
                                           int* __restrict__ idx_out,
                                           int* __restrict__ flagCnt,
                                           int* __restrict__ flagList,
                                           float* __restrict__ lossP,
                                           float* __restrict__ maskP, int N) {
    int t = blockIdx.x * 256 + threadIdx.x;
    float mk = xmask[t];
    float b1 = 3.4e38f, b2 = 3.4e38f;
    int bi = 0;
#pragma unroll
    for (int s = 0; s < 2; ++s) {
        size_t o = (size_t)s * N + t;
        float v1 = pb1[o], v2 = pb2[o];
        int vi = pidx[o];
        if (v1 < b1) { b2 = fminf(b1, v2); b1 = v1; bi = vi; }
        else b2 = fminf(b2, v1);
    }
    idx_out[t] = bi;
    if (b2 - b1 < MARGIN) {
        int p = atomicAdd(flagCnt, 1);
        flagList[p] = t;
    }
    float li = mk * mk * (xnrm[t] + b1);
    __shared__ float sred[256];
    sred[threadIdx.x] = li;
    __syncthreads();
#pragma unroll
    for (int s = 128; s > 0; s >>= 1) {
        if (threadIdx.x < s) sred[threadIdx.x] += sred[threadIdx.x + s];
        __syncthreads();
    }
    if (threadIdx.x == 0) lossP[blockIdx.x] = sred[0];
    __syncthreads();
    sred[threadIdx.x] = mk;
    __syncthreads();
#pragma unroll
    for (int s = 128; s > 0; s >>= 1) {
        if (threadIdx.x < s) sred[threadIdx.x] += sred[threadIdx.x + s];
        __syncthreads();
    }
    if (threadIdx.x == 0) maskP[blockIdx.x] = sred[0];
}

// kF: bit-exact np-f32 rescan for flagged tokens, 4 tokens per wave.
__global__ __launch_bounds__(256) void kF(const float* __restrict__ x,
                                          const float* __restrict__ xmask,
                                          const float* __restrict__ embT,
                                          const float* __restrict__ sumE,
                                          const int* __restrict__ flagCnt,
                                          const int* __restrict__ flagList,
                                          int* __restrict__ idx_out) {
    int wave = (blockIdx.x * 256 + threadIdx.x) >> 6;
    int lane = threadIdx.x & 63;
    int nW = gridDim.x * 4;
    int cnt = *flagCnt;
    for (int j = wave * 4; j < cnt; j += nW * 4) {
        int t[4]; float mk[4], sx[4];
#pragma unroll
        for (int q = 0; q < 4; ++q) {
            int jj = (j + q < cnt) ? (j + q) : j;
            t[q] = flagList[jj];
            mk[q] = xmask[t[q]];
            sx[q] = np_pairwise_sumsq128(x + (size_t)t[q] * D_EMB, mk[q]);
        }
        float acc[4][8];
#pragma unroll
        for (int q = 0; q < 4; ++q)
#pragma unroll
            for (int cb = 0; cb < 8; ++cb) acc[q][cb] = 0.f;
        for (int i = 0; i < D_EMB; ++i) {
            float ev[8];
#pragma unroll
            for (int cb = 0; cb < 8; ++cb) ev[cb] = embT[i * M_CODES + cb * 64 + lane];
            float xq[4];
#pragma unroll
            for (int q = 0; q < 4; ++q) xq[q] = __fmul_rn(x[(size_t)t[q] * D_EMB + i], mk[q]);
#pragma unroll
            for (int q = 0; q < 4; ++q)
#pragma unroll
                for (int cb = 0; cb < 8; ++cb)
                    acc[q][cb] = __fmaf_rn(xq[q], ev[cb], acc[q][cb]);
        }
#pragma unroll
        for (int q = 0; q < 4; ++q) {
            float best = 3.4e38f;
            int bq = 0x7fffffff;
#pragma unroll
            for (int cb = 0; cb < 8; ++cb) {
                int c = cb * 64 + lane;
                float d = __fsub_rn(__fadd_rn(sumE[c], sx[q]), __fmul_rn(2.f, acc[q][cb]));
                if (d < best || (d == best && c < bq)) { best = d; bq = c; }
            }
#pragma unroll
            for (int off = 32; off > 0; off >>= 1) {
                float s2 = __shfl_xor(best, off, 64);
                int i2 = __shfl_xor(bq, off, 64);
                if (s2 < best || (s2 == best && i2 < bq)) { best = s2; bq = i2; }
            }
            if (lane == 0) idx_out[t[q]] = bq;
        }
    }
}

// kScat: LDS-accumulated scatter + fused q_st write. (R17-validated.)
__global__ __launch_bounds__(256) void kScat(const float* __restrict__ x,
                                             const float* __restrict__ emb,
                                             const float* __restrict__ xmask,
                                             const int* __restrict__ idx,
                                             float* __restrict__ q_st,
                                             float* __restrict__ partialD,
                                             float* __restrict__ accc,
                                             int N, int nch) {
    __shared__ float accD[16 * M_CODES];   // [dd][code]
    __shared__ float accC[M_CODES];
    int bid = blockIdx.x;
    int q = bid / nch, ch = bid - q * nch;   // q = dim-slice 0..7
    int tid = threadIdx.x;
    for (int i = tid; i < 16 * M_CODES; i += 256) accD[i] = 0.f;
    if (q == 0)
        for (int i = tid; i < M_CODES; i += 256) accC[i] = 0.f;
    __syncthreads();
    int tl = tid >> 1, dl = tid & 1;
    int base = ch * SCHUNK;
    for (int it = 0; it < SCHUNK / 128; ++it) {
        int t = base + it * 128 + tl;
        if (t < N) {
            int id = idx[t];
            float mk = xmask[t];
            const float4* xp = reinterpret_cast<const float4*>(
                x + (size_t)t * D_EMB + q * 16 + dl * 8);
            const float4* ep = reinterpret_cast<const float4*>(
                emb + (size_t)id * D_EMB + q * 16 + dl * 8);
            float4 xv0 = xp[0], xv1 = xp[1];
            float4 ev0 = ep[0], ev1 = ep[1];
            float4 o0, o1;
            o0.x = ev0.x * mk; o0.y = ev0.y * mk; o0.z = ev0.z * mk; o0.w = ev0.w * mk;
            o1.x = ev1.x * mk; o1.y = ev1.y * mk; o1.z = ev1.z * mk; o1.w = ev1.w * mk;
            float4* qp = reinterpret_cast<float4*>(
                q_st + (size_t)t * D_EMB + q * 16 + dl * 8);
            qp[0] = o0; qp[1] = o1;
            float vx[8] = {xv0.x * mk, xv0.y * mk, xv0.z * mk, xv0.w * mk,
                           xv1.x * mk, xv1.y * mk, xv1.z * mk, xv1.w * mk};
            int d0 = dl * 8;
#pragma unroll
            for (int j = 0; j < 8; ++j)
                atomicAdd(&accD[(d0 + j) * M_CODES + id], vx[j]);
            if (q == 0 && dl == 0) atomicAdd(&accC[id], 1.f);
        }
    }
    __syncthreads();
    float* pD = partialD + (size_t)bid * (16 * M_CODES);
    for (int i = tid; i < 16 * M_CODES; i += 256) pD[i] = accD[i];
    if (q == 0)
        for (int i = tid; i < M_CODES; i += 256) atomicAdd(&accc[i], accC[i]);
}

// kC: count normalization + loss finalize.
__global__ __launch_bounds__(512) void kC(const float* __restrict__ counts,
                                          const float* __restrict__ ema_count,
                                          float* __restrict__ new_count_out,
                                          float* __restrict__ norm_ws,
                                          const float* __restrict__ lossP,
                                          const float* __restrict__ maskP,
                                          float* __restrict__ loss_out, int nP) {
    __shared__ float red[512];
    int t = threadIdx.x;
    float raw = 0.999f * ema_count[t] + 0.001f * counts[t];
    red[t] = raw;
    __syncthreads();
#pragma unroll
    for (int s = 256; s > 0; s >>= 1) {
        if (t < s) red[t] += red[t + s];
        __syncthreads();
    }
    float nsum = red[0];
    __syncthreads();
    float norm = (raw + 1e-5f) / (nsum + (float)M_CODES * 1e-5f) * nsum;
    new_count_out[t] = norm;
    norm_ws[t] = norm;

    float lp = 0.f, mp = 0.f;
    for (int i = t; i < nP; i += 512) { lp += lossP[i]; mp += maskP[i]; }
    red[t] = lp;
    __syncthreads();
#pragma unroll
    for (int s = 256; s > 0; s >>= 1) {
        if (t < s) red[t] += red[t + s];
        __syncthreads();
    }
    float S = red[0];
    __syncthreads();
    red[t] = mp;
    __syncthreads();
#pragma unroll
    for (int s = 256; s > 0; s >>= 1) {
        if (t < s) red[t] += red[t + s];
        __syncthreads();
    }
    if (t == 0) loss_out[0] = 0.25f * S / (red[0] * (float)D_EMB);
}

// kWD2: reduce chunk partials + EMA + divide (code-fastest coalesced reads).
__global__ void kWD2(const float* __restrict__ partialD,
                     const float* __restrict__ ema_w,
                     const float* __restrict__ norm_ws,
                     float* __restrict__ new_w, float* __restrict__ new_emb,
                     int nch) {
    int i = blockIdx.x * 256 + threadIdx.x;   // 65536 elements
    int c = i & 511;          // code (fastest)
    int d = i >> 9;           // dim 0..127
    int q = d >> 4, dd = d & 15;
    float s = 0.f;
    for (int ch = 0; ch < nch; ++ch)
        s += partialD[(size_t)(q * nch + ch) * (16 * M_CODES) + dd * M_CODES + c];
    size_t o = (size_t)c * D_EMB + d;
    float w = 0.999f * ema_w[o] + 0.001f * s;
    new_w[o] = w;
    new_emb[o] = w / norm_ws[c];
}

extern "C" void kernel_launch(void* const* d_in, const int* in_sizes, int n_in,
                              void* d_out, int out_size, void* d_ws, size_t ws_size,
                              hipStream_t stream) {
    const float* x = (const float*)d_in[0];
    const float* xmask = (const float*)d_in[1];
    const float* emb = (const float*)d_in[2];
    const float* ema_count = (const float*)d_in[3];
    const float* ema_weight = (const float*)d_in[4];
    int N = in_sizes[0] / D_EMB;

    float* out = (float*)d_out;
    float* q_st = out;
    float* loss = out + (size_t)N * D_EMB;
    float* new_emb = loss + 1;
    float* new_cnt = new_emb + M_CODES * D_EMB;
    float* new_w = new_cnt + M_CODES;

    int nGrp = N / 32;                         // 2048 (32 tokens per group)
    int nch = (N + SCHUNK - 1) / SCHUNK;       // 64
    int nA2 = N / 256;                         // 256 merge blocks
    float* fws = (float*)d_ws;
    int* idx = (int*)fws;                      // N
    float* counts = fws + N;                   // 512 (accc)
    float* norm = counts + M_CODES;            // 512
    float* lossP = norm + M_CODES;             // nA2
    float* maskP = lossP + nA2;                // nA2
    float* sumE = maskP + nA2;                 // 512
    int* flagCnt = (int*)(sumE + M_CODES);     // 4
    int* flagList = flagCnt + 4;               // N
    float* xnrm = (float*)(flagList + N);      // N
    float* pb1 = xnrm + N;                     // 2N
    float* pb2 = pb1 + 2 * (size_t)N;          // 2N
    int* pidx = (int*)(pb2 + 2 * (size_t)N);   // 2N
    float* embT = (float*)(pidx + 2 * (size_t)N);  // 65536
    unsigned short* ebh = (unsigned short*)(embT + M_CODES * D_EMB);  // 65536 u16
    unsigned short* ebl = ebh + M_CODES * D_EMB;                      // 65536 u16
    float* partialD = (float*)(ebl + M_CODES * D_EMB);  // 8*nch*16*512 f32 (16MB)

    hipLaunchKernelGGL(kSZ, dim3(128), dim3(256), 0, stream,
                       emb, sumE, embT, ebh, ebl, counts, flagCnt);
    hipLaunchKernelGGL(kA, dim3(nGrp / 2), dim3(256), 0, stream, x, xmask, ebh,
                       ebl, sumE, pb1, pb2, pidx, xnrm, N);
    hipLaunchKernelGGL(kA2, dim3(nA2), dim3(256), 0, stream, pb1, pb2, pidx,
                       xnrm, xmask, idx, flagCnt, flagList, lossP, maskP, N);
    hipLaunchKernelGGL(kF, dim3(512), dim3(256), 0, stream, x, xmask, embT, sumE,
                       flagCnt, flagList, idx);
    hipLaunchKernelGGL(kScat, dim3(8 * nch), dim3(256), 0, stream, x, emb, xmask,
                       idx, q_st, partialD, counts, N, nch);
    hipLaunchKernelGGL(kC, dim3(1), dim3(512), 0, stream, counts, ema_count,
                       new_cnt, norm, lossP, maskP, loss, nA2);
    hipLaunchKernelGGL(kWD2, dim3(M_CODES * D_EMB / 256), dim3(256), 0, stream,
                       partialD, ema_weight, norm, new_w, new_emb, nch);
}

// Round 20
// 196.747 us; speedup vs baseline: 2.2298x; 1.1431x over previous
//
#include <hip/hip_runtime.h>

#define M_CODES 512
#define D_EMB 128
#define D4 32
#define MARGIN 5e-5f
#define SCHUNK 1024   // tokens per scatter chunk

typedef short bf16x8 __attribute__((ext_vector_type(8)));
typedef float f32x4 __attribute__((ext_vector_type(4)));

__device__ __forceinline__ unsigned short f2bf(float f) {  // RNE f32->bf16
    unsigned u = __float_as_uint(f);
    u += 0x7fffu + ((u >> 16) & 1u);
    return (unsigned short)(u >> 16);
}
__device__ __forceinline__ float bf2f(unsigned short h) {
    return __uint_as_float(((unsigned)h) << 16);
}

// numpy pairwise sum (n=128): 8 strided accumulators + tree. (R6-validated,
// exact original form — _rn intrinsics are non-contractible by themselves.)
__device__ __forceinline__ float np_pairwise_sumsq128(const float* __restrict__ a,
                                                      float scale) {
    float r[8];
#pragma unroll
    for (int j = 0; j < 8; ++j) {
        float v = __fmul_rn(a[j], scale);
        r[j] = __fmul_rn(v, v);
    }
    for (int i = 8; i < 128; i += 8) {
#pragma unroll
        for (int j = 0; j < 8; ++j) {
            float v = __fmul_rn(a[i + j], scale);
            r[j] = __fadd_rn(r[j], __fmul_rn(v, v));
        }
    }
    return __fadd_rn(__fadd_rn(__fadd_rn(r[0], r[1]), __fadd_rn(r[2], r[3])),
                     __fadd_rn(__fadd_rn(r[4], r[5]), __fadd_rn(r[6], r[7])));
}

// kSZ: parallel setup (R17-validated). Wave per code; lanes 0..7 replicate the
// np pairwise-8 pattern exactly, shuffle tree in exact tree order.
__global__ __launch_bounds__(256) void kSZ(const float* __restrict__ emb,
                                           float* __restrict__ sumE,
                                           float* __restrict__ embT,
                                           unsigned short* __restrict__ ebh,
                                           unsigned short* __restrict__ ebl,
                                           float* __restrict__ accc,
                                           int* __restrict__ flagCnt) {
    int tid = threadIdx.x, wid = tid >> 6, lane = tid & 63;
    int m = blockIdx.x * 4 + wid;            // 0..511
    int gi = blockIdx.x * 256 + tid;
    if (gi < M_CODES) accc[gi] = 0.f;
    if (gi == 0) *flagCnt = 0;
    const float* er = emb + (size_t)m * D_EMB;
    float r = 0.f;
    if (lane < 8) {
        float v = __fmul_rn(er[lane], 1.0f);
        r = __fmul_rn(v, v);
        for (int i = 1; i < 16; ++i) {
            float w = __fmul_rn(er[8 * i + lane], 1.0f);
            r = __fadd_rn(r, __fmul_rn(w, w));
        }
    }
    float s1 = __fadd_rn(r, __shfl_xor(r, 1, 64));
    float s2 = __fadd_rn(s1, __shfl_xor(s1, 2, 64));
    float s3 = __fadd_rn(s2, __shfl_xor(s2, 4, 64));
    if (lane == 0) sumE[m] = s3;
#pragma unroll
    for (int dd = lane; dd < D_EMB; dd += 64) {
        float e = er[dd];
        embT[dd * M_CODES + m] = e;
        unsigned short hh = f2bf(e);
        ebh[(size_t)m * D_EMB + dd] = hh;
        ebl[(size_t)m * D_EMB + dd] = f2bf(e - bf2f(hh));
    }
}

// kA screen via split-bf16 MFMA + LDS-staged codebook (R18 design).
// Block = 4 waves x 32 tokens = 128 tokens marching in LOCKSTEP through 32
// code-tiles; each 16-code h+l tile (8 KB) double-buffer staged in LDS by all
// 256 threads (R18 counters: per-wave private codebook streaming thrashed L1
// -> 512 MB L2 traffic, 82 us at MfmaUtil 12%). XOR swizzle slot^=(m&7) on
// both stage-write and frag-read -> conflict-free b128.
__global__ __launch_bounds__(256) void kA(const float* __restrict__ x,
                                          const float* __restrict__ xmask,
                                          const unsigned short* __restrict__ ebh,
                                          const unsigned short* __restrict__ ebl,
                                          const float* __restrict__ sumE,
                                          int* __restrict__ idx_out,
                                          int* __restrict__ flagCnt,
                                          int* __restrict__ flagList,
                                          float* __restrict__ lossW,
                                          float* __restrict__ maskW, int N) {
    __shared__ unsigned short hb[2][2048];   // 4 KB each buf (16 codes x 128d)
    __shared__ unsigned short lb[2][2048];
    __shared__ float xnS[4][32], mkS[4][32];
    int tid = threadIdx.x;
    int wid = tid >> 6, lane = tid & 63;
    int m = lane & 15, kg = lane >> 4;
    int tok0 = blockIdx.x * 128 + wid * 32;

    // ---- A fragments: 32 tokens (two 16-token tiles), split-bf16 ----
    bf16x8 ah0[4], al0[4], ah1[4], al1[4];
    float xn0 = 0.f, xn1 = 0.f;
    float mk0 = xmask[tok0 + m], mk1 = xmask[tok0 + 16 + m];
#pragma unroll
    for (int ks = 0; ks < 4; ++ks) {
        const float4* p0 = reinterpret_cast<const float4*>(
            x + (size_t)(tok0 + m) * D_EMB + ks * 32 + kg * 8);
        const float4* p1 = reinterpret_cast<const float4*>(
            x + (size_t)(tok0 + 16 + m) * D_EMB + ks * 32 + kg * 8);
        float4 a0 = p0[0], a1 = p0[1], c0 = p1[0], c1 = p1[1];
        float e0[8] = {a0.x, a0.y, a0.z, a0.w, a1.x, a1.y, a1.z, a1.w};
        float e1[8] = {c0.x, c0.y, c0.z, c0.w, c1.x, c1.y, c1.z, c1.w};
        bf16x8 h0, l0, h1, l1;
#pragma unroll
        for (int j = 0; j < 8; ++j) {
            float v0 = e0[j] * mk0;
            xn0 = fmaf(v0, v0, xn0);
            unsigned short hh0 = f2bf(v0);
            h0[j] = (short)hh0;
            l0[j] = (short)f2bf(v0 - bf2f(hh0));
            float v1 = e1[j] * mk1;
            xn1 = fmaf(v1, v1, xn1);
            unsigned short hh1 = f2bf(v1);
            h1[j] = (short)hh1;
            l1[j] = (short)f2bf(v1 - bf2f(hh1));
        }
        ah0[ks] = h0; al0[ks] = l0; ah1[ks] = h1; al1[ks] = l1;
    }
    xn0 += __shfl_xor(xn0, 16, 64);
    xn0 += __shfl_xor(xn0, 32, 64);
    xn1 += __shfl_xor(xn1, 16, 64);
    xn1 += __shfl_xor(xn1, 32, 64);
    if (kg == 0) {
        xnS[wid][m] = xn0; mkS[wid][m] = mk0;
        xnS[wid][16 + m] = xn1; mkS[wid][16 + m] = mk1;
    }

    float b1[2][4], b2[2][4];
    int bi[2][4];
#pragma unroll
    for (int tt = 0; tt < 2; ++tt)
#pragma unroll
        for (int r = 0; r < 4; ++r) {
            b1[tt][r] = 3.4e38f; b2[tt][r] = 3.4e38f; bi[tt][r] = 0x7fffffff;
        }

    // staging: thread -> (code mo = tid>>4, 16B-slot sl = tid&15)
    int mo = tid >> 4, sl = tid & 15;
    int dstIdx = mo * 128 + (sl >> 3) * 64 + ((sl & 7) ^ (mo & 7)) * 8;  // ushorts
#define STAGE(b, ct)                                                           \
    {                                                                          \
        const float4* sh = reinterpret_cast<const float4*>(                    \
            ebh + (size_t)((ct) * 16 + mo) * D_EMB + sl * 8);                  \
        const float4* sv = reinterpret_cast<const float4*>(                    \
            ebl + (size_t)((ct) * 16 + mo) * D_EMB + sl * 8);                  \
        *reinterpret_cast<float4*>(&hb[b][dstIdx]) = *sh;                      \
        *reinterpret_cast<float4*>(&lb[b][dstIdx]) = *sv;                      \
    }

    STAGE(0, 0);
    __syncthreads();
    for (int ct = 0; ct < 32; ++ct) {
        int cur = ct & 1;
        if (ct < 31) STAGE(cur ^ 1, ct + 1);
        // fragment reads: lane (m,kg), ks -> row r=ks>>1, slot s=(ks&1)*4+kg
        bf16x8 bh[4], bl[4];
#pragma unroll
        for (int ks = 0; ks < 4; ++ks) {
            int off = m * 128 + (ks >> 1) * 64 + ((((ks & 1) * 4 + kg)) ^ (m & 7)) * 8;
            bh[ks] = *reinterpret_cast<const bf16x8*>(&hb[cur][off]);
            bl[ks] = *reinterpret_cast<const bf16x8*>(&lb[cur][off]);
        }
        f32x4 accA0 = {0.f, 0.f, 0.f, 0.f}, accB0 = {0.f, 0.f, 0.f, 0.f};
        f32x4 accA1 = {0.f, 0.f, 0.f, 0.f}, accB1 = {0.f, 0.f, 0.f, 0.f};
#pragma unroll
        for (int ks = 0; ks < 2; ++ks) {
            accA0 = __builtin_amdgcn_mfma_f32_16x16x32_bf16(ah0[ks], bh[ks], accA0, 0, 0, 0);
            accA0 = __builtin_amdgcn_mfma_f32_16x16x32_bf16(al0[ks], bh[ks], accA0, 0, 0, 0);
            accA0 = __builtin_amdgcn_mfma_f32_16x16x32_bf16(ah0[ks], bl[ks], accA0, 0, 0, 0);
            accA1 = __builtin_amdgcn_mfma_f32_16x16x32_bf16(ah1[ks], bh[ks], accA1, 0, 0, 0);
            accA1 = __builtin_amdgcn_mfma_f32_16x16x32_bf16(al1[ks], bh[ks], accA1, 0, 0, 0);
            accA1 = __builtin_amdgcn_mfma_f32_16x16x32_bf16(ah1[ks], bl[ks], accA1, 0, 0, 0);
        }
#pragma unroll
        for (int ks = 2; ks < 4; ++ks) {
            accB0 = __builtin_amdgcn_mfma_f32_16x16x32_bf16(ah0[ks], bh[ks], accB0, 0, 0, 0);
            accB0 = __builtin_amdgcn_mfma_f32_16x16x32_bf16(al0[ks], bh[ks], accB0, 0, 0, 0);
            accB0 = __builtin_amdgcn_mfma_f32_16x16x32_bf16(ah0[ks], bl[ks], accB0, 0, 0, 0);
            accB1 = __builtin_amdgcn_mfma_f32_16x16x32_bf16(ah1[ks], bh[ks], accB1, 0, 0, 0);
            accB1 = __builtin_amdgcn_mfma_f32_16x16x32_bf16(al1[ks], bh[ks], accB1, 0, 0, 0);
            accB1 = __builtin_amdgcn_mfma_f32_16x16x32_bf16(ah1[ks], bl[ks], accB1, 0, 0, 0);
        }
        int c = ct * 16 + m;
        float sE = sumE[c];
#pragma unroll
        for (int r = 0; r < 4; ++r) {
            float s0 = fmaf(-2.f, accA0[r] + accB0[r], sE);
            if (s0 < b1[0][r]) { b2[0][r] = b1[0][r]; b1[0][r] = s0; bi[0][r] = c; }
            else if (s0 < b2[0][r]) b2[0][r] = s0;
            float s1 = fmaf(-2.f, accA1[r] + accB1[r], sE);
            if (s1 < b1[1][r]) { b2[1][r] = b1[1][r]; b1[1][r] = s1; bi[1][r] = c; }
            else if (s1 < b2[1][r]) b2[1][r] = s1;
        }
        __syncthreads();
    }
#undef STAGE
    // merge across the 16 col-lanes (codes)
#pragma unroll
    for (int off = 1; off <= 8; off <<= 1) {
#pragma unroll
        for (int tt = 0; tt < 2; ++tt)
#pragma unroll
            for (int r = 0; r < 4; ++r) {
                float o1 = __shfl_xor(b1[tt][r], off, 64);
                float o2 = __shfl_xor(b2[tt][r], off, 64);
                int oi = __shfl_xor(bi[tt][r], off, 64);
                if (o1 < b1[tt][r] || (o1 == b1[tt][r] && oi < bi[tt][r])) {
                    b2[tt][r] = fminf(b1[tt][r], o2); b1[tt][r] = o1; bi[tt][r] = oi;
                } else {
                    b2[tt][r] = fminf(b2[tt][r], o1);
                }
            }
    }
    float liS = 0.f, mkT = 0.f;
#pragma unroll
    for (int tt = 0; tt < 2; ++tt)
#pragma unroll
        for (int r = 0; r < 4; ++r) {
            int row = kg * 4 + r;
            float mkr = mkS[wid][tt * 16 + row], xnr = xnS[wid][tt * 16 + row];
            liS += mkr * mkr * (xnr + b1[tt][r]);
            mkT += mkr;
            if (m == 0) {
                int tokr = tok0 + tt * 16 + row;
                idx_out[tokr] = bi[tt][r];
                if (b2[tt][r] - b1[tt][r] < MARGIN) {
                    int pp = atomicAdd(flagCnt, 1);
                    flagList[pp] = tokr;
                }
            }
        }
    liS += __shfl_xor(liS, 16, 64);
    liS += __shfl_xor(liS, 32, 64);
    mkT += __shfl_xor(mkT, 16, 64);
    mkT += __shfl_xor(mkT, 32, 64);
    if (lane == 0) {
        int grp = blockIdx.x * 4 + wid;
        lossW[grp] = liS;
        maskW[grp] = mkT;
    }
}

// kF: bit-exact np-f32 rescan for flagged tokens, 4 tokens per wave.
__global__ __launch_bounds__(256) void kF(const float* __restrict__ x,
                                          const float* __restrict__ xmask,
                                          const float* __restrict__ embT,
                                          const float* __restrict__ sumE,
                                          const int* __restrict__ flagCnt,
                                          const int* __restrict__ flagList,
                                          int* __restrict__ idx_out) {
    int wave = (blockIdx.x * 256 + threadIdx.x) >> 6;
    int lane = threadIdx.x & 63;
    int nW = gridDim.x * 4;
    int cnt = *flagCnt;
    for (int j = wave * 4; j < cnt; j += nW * 4) {
        int t[4]; float mk[4], sx[4];
#pragma unroll
        for (int q = 0; q < 4; ++q) {
            int jj = (j + q < cnt) ? (j + q) : j;
            t[q] = flagList[jj];
            mk[q] = xmask[t[q]];
            sx[q] = np_pairwise_sumsq128(x + (size_t)t[q] * D_EMB, mk[q]);
        }
        float acc[4][8];
#pragma unroll
        for (int q = 0; q < 4; ++q)
#pragma unroll
            for (int cb = 0; cb < 8; ++cb) acc[q][cb] = 0.f;
        for (int i = 0; i < D_EMB; ++i) {
            float ev[8];
#pragma unroll
            for (int cb = 0; cb < 8; ++cb) ev[cb] = embT[i * M_CODES + cb * 64 + lane];
            float xq[4];
#pragma unroll
            for (int q = 0; q < 4; ++q) xq[q] = __fmul_rn(x[(size_t)t[q] * D_EMB + i], mk[q]);
#pragma unroll
            for (int q = 0; q < 4; ++q)
#pragma unroll
                for (int cb = 0; cb < 8; ++cb)
                    acc[q][cb] = __fmaf_rn(xq[q], ev[cb], acc[q][cb]);
        }
#pragma unroll
        for (int q = 0; q < 4; ++q) {
            float best = 3.4e38f;
            int bq = 0x7fffffff;
#pragma unroll
            for (int cb = 0; cb < 8; ++cb) {
                int c = cb * 64 + lane;
                float d = __fsub_rn(__fadd_rn(sumE[c], sx[q]), __fmul_rn(2.f, acc[q][cb]));
                if (d < best || (d == best && c < bq)) { best = d; bq = c; }
            }
#pragma unroll
            for (int off = 32; off > 0; off >>= 1) {
                float s2 = __shfl_xor(best, off, 64);
                int i2 = __shfl_xor(bq, off, 64);
                if (s2 < best || (s2 == best && i2 < bq)) { best = s2; bq = i2; }
            }
            if (lane == 0) idx_out[t[q]] = bq;
        }
    }
}

// kScat: LDS-accumulated scatter + fused q_st write. (R17-validated.)
__global__ __launch_bounds__(256) void kScat(const float* __restrict__ x,
                                             const float* __restrict__ emb,
                                             const float* __restrict__ xmask,
                                             const int* __restrict__ idx,
                                             float* __restrict__ q_st,
                                             float* __restrict__ partialD,
                                             float* __restrict__ accc,
                                             int N, int nch) {
    __shared__ float accD[16 * M_CODES];   // [dd][code]
    __shared__ float accC[M_CODES];
    int bid = blockIdx.x;
    int q = bid / nch, ch = bid - q * nch;   // q = dim-slice 0..7
    int tid = threadIdx.x;
    for (int i = tid; i < 16 * M_CODES; i += 256) accD[i] = 0.f;
    if (q == 0)
        for (int i = tid; i < M_CODES; i += 256) accC[i] = 0.f;
    __syncthreads();
    int tl = tid >> 1, dl = tid & 1;
    int base = ch * SCHUNK;
    for (int it = 0; it < SCHUNK / 128; ++it) {
        int t = base + it * 128 + tl;
        if (t < N) {
            int id = idx[t];
            float mk = xmask[t];
            const float4* xp = reinterpret_cast<const float4*>(
                x + (size_t)t * D_EMB + q * 16 + dl * 8);
            const float4* ep = reinterpret_cast<const float4*>(
                emb + (size_t)id * D_EMB + q * 16 + dl * 8);
            float4 xv0 = xp[0], xv1 = xp[1];
            float4 ev0 = ep[0], ev1 = ep[1];
            float4 o0, o1;
            o0.x = ev0.x * mk; o0.y = ev0.y * mk; o0.z = ev0.z * mk; o0.w = ev0.w * mk;
            o1.x = ev1.x * mk; o1.y = ev1.y * mk; o1.z = ev1.z * mk; o1.w = ev1.w * mk;
            float4* qp = reinterpret_cast<float4*>(
                q_st + (size_t)t * D_EMB + q * 16 + dl * 8);
            qp[0] = o0; qp[1] = o1;
            float vx[8] = {xv0.x * mk, xv0.y * mk, xv0.z * mk, xv0.w * mk,
                           xv1.x * mk, xv1.y * mk, xv1.z * mk, xv1.w * mk};
            int d0 = dl * 8;
#pragma unroll
            for (int j = 0; j < 8; ++j)
                atomicAdd(&accD[(d0 + j) * M_CODES + id], vx[j]);
            if (q == 0 && dl == 0) atomicAdd(&accC[id], 1.f);
        }
    }
    __syncthreads();
    float* pD = partialD + (size_t)bid * (16 * M_CODES);
    for (int i = tid; i < 16 * M_CODES; i += 256) pD[i] = accD[i];
    if (q == 0)
        for (int i = tid; i < M_CODES; i += 256) atomicAdd(&accc[i], accC[i]);
}

// kC: count normalization + loss finalize.
__global__ __launch_bounds__(512) void kC(const float* __restrict__ counts,
                                          const float* __restrict__ ema_count,
                                          float* __restrict__ new_count_out,
                                          float* __restrict__ norm_ws,
                                          const float* __restrict__ lossP,
                                          const float* __restrict__ maskP,
                                          float* __restrict__ loss_out, int nP) {
    __shared__ float red[512];
    int t = threadIdx.x;
    float raw = 0.999f * ema_count[t] + 0.001f * counts[t];
    red[t] = raw;
    __syncthreads();
#pragma unroll
    for (int s = 256; s > 0; s >>= 1) {
        if (t < s) red[t] += red[t + s];
        __syncthreads();
    }
    float nsum = red[0];
    __syncthreads();
    float norm = (raw + 1e-5f) / (nsum + (float)M_CODES * 1e-5f) * nsum;
    new_count_out[t] = norm;
    norm_ws[t] = norm;

    float lp = 0.f, mp = 0.f;
    for (int i = t; i < nP; i += 512) { lp += lossP[i]; mp += maskP[i]; }
    red[t] = lp;
    __syncthreads();
#pragma unroll
    for (int s = 256; s > 0; s >>= 1) {
        if (t < s) red[t] += red[t + s];
        __syncthreads();
    }
    float S = red[0];
    __syncthreads();
    red[t] = mp;
    __syncthreads();
#pragma unroll
    for (int s = 256; s > 0; s >>= 1) {
        if (t < s) red[t] += red[t + s];
        __syncthreads();
    }
    if (t == 0) loss_out[0] = 0.25f * S / (red[0] * (float)D_EMB);
}

// kWD2: reduce chunk partials + EMA + divide (code-fastest coalesced reads).
__global__ void kWD2(const float* __restrict__ partialD,
                     const float* __restrict__ ema_w,
                     const float* __restrict__ norm_ws,
                     float* __restrict__ new_w, float* __restrict__ new_emb,
                     int nch) {
    int i = blockIdx.x * 256 + threadIdx.x;   // 65536 elements
    int c = i & 511;          // code (fastest)
    int d = i >> 9;           // dim 0..127
    int q = d >> 4, dd = d & 15;
    float s = 0.f;
    for (int ch = 0; ch < nch; ++ch)
        s += partialD[(size_t)(q * nch + ch) * (16 * M_CODES) + dd * M_CODES + c];
    size_t o = (size_t)c * D_EMB + d;
    float w = 0.999f * ema_w[o] + 0.001f * s;
    new_w[o] = w;
    new_emb[o] = w / norm_ws[c];
}

extern "C" void kernel_launch(void* const* d_in, const int* in_sizes, int n_in,
                              void* d_out, int out_size, void* d_ws, size_t ws_size,
                              hipStream_t stream) {
    const float* x = (const float*)d_in[0];
    const float* xmask = (const float*)d_in[1];
    const float* emb = (const float*)d_in[2];
    const float* ema_count = (const float*)d_in[3];
    const float* ema_weight = (const float*)d_in[4];
    int N = in_sizes[0] / D_EMB;

    float* out = (float*)d_out;
    float* q_st = out;
    float* loss = out + (size_t)N * D_EMB;
    float* new_emb = loss + 1;
    float* new_cnt = new_emb + M_CODES * D_EMB;
    float* new_w = new_cnt + M_CODES;

    int nGrp = N / 32;                         // 2048 wave groups
    int nch = (N + SCHUNK - 1) / SCHUNK;       // 64
    float* fws = (float*)d_ws;
    int* idx = (int*)fws;                      // N
    float* counts = fws + N;                   // 512 (accc)
    float* norm = counts + M_CODES;            // 512
    float* lossP = norm + M_CODES;             // nGrp
    float* maskP = lossP + nGrp;               // nGrp
    float* sumE = maskP + nGrp;                // 512
    int* flagCnt = (int*)(sumE + M_CODES);     // 4
    int* flagList = flagCnt + 4;               // N
    float* embT = (float*)(flagList + N);      // 65536
    unsigned short* ebh = (unsigned short*)(embT + M_CODES * D_EMB);  // 65536 u16
    unsigned short* ebl = ebh + M_CODES * D_EMB;                      // 65536 u16
    float* partialD = (float*)(ebl + M_CODES * D_EMB);  // 8*nch*16*512 f32 (16MB)

    hipLaunchKernelGGL(kSZ, dim3(128), dim3(256), 0, stream,
                       emb, sumE, embT, ebh, ebl, counts, flagCnt);
    hipLaunchKernelGGL(kA, dim3(N / 128), dim3(256), 0, stream, x, xmask, ebh,
                       ebl, sumE, idx, flagCnt, flagList, lossP, maskP, N);
    hipLaunchKernelGGL(kF, dim3(512), dim3(256), 0, stream, x, xmask, embT, sumE,
                       flagCnt, flagList, idx);
    hipLaunchKernelGGL(kScat, dim3(8 * nch), dim3(256), 0, stream, x, emb, xmask,
                       idx, q_st, partialD, counts, N, nch);
    hipLaunchKernelGGL(kC, dim3(1), dim3(512), 0, stream, counts, ema_count,
                       new_cnt, norm, lossP, maskP, loss, nGrp);
    hipLaunchKernelGGL(kWD2, dim3(M_CODES * D_EMB / 256), dim3(256), 0, stream,
                       partialD, ema_weight, norm, new_w, new_emb, nch);
}

// Round 21
// 153.494 us; speedup vs baseline: 2.8581x; 1.2818x over previous
//
#include <hip/hip_runtime.h>

#define M_CODES 512
#define D_EMB 128
#define D4 32
#define MARGIN 5e-5f
#define SCHUNK 1024   // tokens per scatter chunk

typedef short bf16x8 __attribute__((ext_vector_type(8)));
typedef float f32x4 __attribute__((ext_vector_type(4)));

__device__ __forceinline__ unsigned short f2bf(float f) {  // RNE f32->bf16
    unsigned u = __float_as_uint(f);
    u += 0x7fffu + ((u >> 16) & 1u);
    return (unsigned short)(u >> 16);
}
__device__ __forceinline__ float bf2f(unsigned short h) {
    return __uint_as_float(((unsigned)h) << 16);
}

// numpy pairwise sum (n=128): 8 strided accumulators + tree. (R6-validated.)
__device__ __forceinline__ float np_pairwise_sumsq128(const float* __restrict__ a,
                                                      float scale) {
    float r[8];
#pragma unroll
    for (int j = 0; j < 8; ++j) {
        float v = __fmul_rn(a[j], scale);
        r[j] = __fmul_rn(v, v);
    }
    for (int i = 8; i < 128; i += 8) {
#pragma unroll
        for (int j = 0; j < 8; ++j) {
            float v = __fmul_rn(a[i + j], scale);
            r[j] = __fadd_rn(r[j], __fmul_rn(v, v));
        }
    }
    return __fadd_rn(__fadd_rn(__fadd_rn(r[0], r[1]), __fadd_rn(r[2], r[3])),
                     __fadd_rn(__fadd_rn(r[4], r[5]), __fadd_rn(r[6], r[7])));
}

// kSZ: parallel setup (R17-validated). Wave per code; lanes 0..7 replicate the
// np pairwise-8 pattern exactly, shuffle tree in exact tree order.
__global__ __launch_bounds__(256) void kSZ(const float* __restrict__ emb,
                                           float* __restrict__ sumE,
                                           float* __restrict__ embT,
                                           unsigned short* __restrict__ ebh,
                                           unsigned short* __restrict__ ebl,
                                           float* __restrict__ accc,
                                           int* __restrict__ flagCnt) {
    int tid = threadIdx.x, wid = tid >> 6, lane = tid & 63;
    int m = blockIdx.x * 4 + wid;            // 0..511
    int gi = blockIdx.x * 256 + tid;
    if (gi < M_CODES) accc[gi] = 0.f;
    if (gi == 0) *flagCnt = 0;
    const float* er = emb + (size_t)m * D_EMB;
    float r = 0.f;
    if (lane < 8) {
        float v = __fmul_rn(er[lane], 1.0f);
        r = __fmul_rn(v, v);
        for (int i = 1; i < 16; ++i) {
            float w = __fmul_rn(er[8 * i + lane], 1.0f);
            r = __fadd_rn(r, __fmul_rn(w, w));
        }
    }
    float s1 = __fadd_rn(r, __shfl_xor(r, 1, 64));
    float s2 = __fadd_rn(s1, __shfl_xor(s1, 2, 64));
    float s3 = __fadd_rn(s2, __shfl_xor(s2, 4, 64));
    if (lane == 0) sumE[m] = s3;
#pragma unroll
    for (int dd = lane; dd < D_EMB; dd += 64) {
        float e = er[dd];
        embT[dd * M_CODES + m] = e;
        unsigned short hh = f2bf(e);
        ebh[(size_t)m * D_EMB + dd] = hh;
        ebl[(size_t)m * D_EMB + dd] = f2bf(e - bf2f(hh));
    }
}

// kA screen via split-bf16 MFMA + LDS-staged codebook (R18/R20-validated).
__global__ __launch_bounds__(256) void kA(const float* __restrict__ x,
                                          const float* __restrict__ xmask,
                                          const unsigned short* __restrict__ ebh,
                                          const unsigned short* __restrict__ ebl,
                                          const float* __restrict__ sumE,
                                          int* __restrict__ idx_out,
                                          int* __restrict__ flagCnt,
                                          int* __restrict__ flagList,
                                          float* __restrict__ lossW,
                                          float* __restrict__ maskW, int N) {
    __shared__ unsigned short hb[2][2048];   // 4 KB each buf (16 codes x 128d)
    __shared__ unsigned short lb[2][2048];
    __shared__ float xnS[4][32], mkS[4][32];
    int tid = threadIdx.x;
    int wid = tid >> 6, lane = tid & 63;
    int m = lane & 15, kg = lane >> 4;
    int tok0 = blockIdx.x * 128 + wid * 32;

    // ---- A fragments: 32 tokens (two 16-token tiles), split-bf16 ----
    bf16x8 ah0[4], al0[4], ah1[4], al1[4];
    float xn0 = 0.f, xn1 = 0.f;
    float mk0 = xmask[tok0 + m], mk1 = xmask[tok0 + 16 + m];
#pragma unroll
    for (int ks = 0; ks < 4; ++ks) {
        const float4* p0 = reinterpret_cast<const float4*>(
            x + (size_t)(tok0 + m) * D_EMB + ks * 32 + kg * 8);
        const float4* p1 = reinterpret_cast<const float4*>(
            x + (size_t)(tok0 + 16 + m) * D_EMB + ks * 32 + kg * 8);
        float4 a0 = p0[0], a1 = p0[1], c0 = p1[0], c1 = p1[1];
        float e0[8] = {a0.x, a0.y, a0.z, a0.w, a1.x, a1.y, a1.z, a1.w};
        float e1[8] = {c0.x, c0.y, c0.z, c0.w, c1.x, c1.y, c1.z, c1.w};
        bf16x8 h0, l0, h1, l1;
#pragma unroll
        for (int j = 0; j < 8; ++j) {
            float v0 = e0[j] * mk0;
            xn0 = fmaf(v0, v0, xn0);
            unsigned short hh0 = f2bf(v0);
            h0[j] = (short)hh0;
            l0[j] = (short)f2bf(v0 - bf2f(hh0));
            float v1 = e1[j] * mk1;
            xn1 = fmaf(v1, v1, xn1);
            unsigned short hh1 = f2bf(v1);
            h1[j] = (short)hh1;
            l1[j] = (short)f2bf(v1 - bf2f(hh1));
        }
        ah0[ks] = h0; al0[ks] = l0; ah1[ks] = h1; al1[ks] = l1;
    }
    xn0 += __shfl_xor(xn0, 16, 64);
    xn0 += __shfl_xor(xn0, 32, 64);
    xn1 += __shfl_xor(xn1, 16, 64);
    xn1 += __shfl_xor(xn1, 32, 64);
    if (kg == 0) {
        xnS[wid][m] = xn0; mkS[wid][m] = mk0;
        xnS[wid][16 + m] = xn1; mkS[wid][16 + m] = mk1;
    }

    float b1[2][4], b2[2][4];
    int bi[2][4];
#pragma unroll
    for (int tt = 0; tt < 2; ++tt)
#pragma unroll
        for (int r = 0; r < 4; ++r) {
            b1[tt][r] = 3.4e38f; b2[tt][r] = 3.4e38f; bi[tt][r] = 0x7fffffff;
        }

    // staging: thread -> (code mo = tid>>4, 16B-slot sl = tid&15)
    int mo = tid >> 4, sl = tid & 15;
    int dstIdx = mo * 128 + (sl >> 3) * 64 + ((sl & 7) ^ (mo & 7)) * 8;  // ushorts
#define STAGE(b, ct)                                                           \
    {                                                                          \
        const float4* sh = reinterpret_cast<const float4*>(                    \
            ebh + (size_t)((ct) * 16 + mo) * D_EMB + sl * 8);                  \
        const float4* sv = reinterpret_cast<const float4*>(                    \
            ebl + (size_t)((ct) * 16 + mo) * D_EMB + sl * 8);                  \
        *reinterpret_cast<float4*>(&hb[b][dstIdx]) = *sh;                      \
        *reinterpret_cast<float4*>(&lb[b][dstIdx]) = *sv;                      \
    }

    STAGE(0, 0);
    __syncthreads();
    for (int ct = 0; ct < 32; ++ct) {
        int cur = ct & 1;
        if (ct < 31) STAGE(cur ^ 1, ct + 1);
        bf16x8 bh[4], bl[4];
#pragma unroll
        for (int ks = 0; ks < 4; ++ks) {
            int off = m * 128 + (ks >> 1) * 64 + ((((ks & 1) * 4 + kg)) ^ (m & 7)) * 8;
            bh[ks] = *reinterpret_cast<const bf16x8*>(&hb[cur][off]);
            bl[ks] = *reinterpret_cast<const bf16x8*>(&lb[cur][off]);
        }
        f32x4 accA0 = {0.f, 0.f, 0.f, 0.f}, accB0 = {0.f, 0.f, 0.f, 0.f};
        f32x4 accA1 = {0.f, 0.f, 0.f, 0.f}, accB1 = {0.f, 0.f, 0.f, 0.f};
#pragma unroll
        for (int ks = 0; ks < 2; ++ks) {
            accA0 = __builtin_amdgcn_mfma_f32_16x16x32_bf16(ah0[ks], bh[ks], accA0, 0, 0, 0);
            accA0 = __builtin_amdgcn_mfma_f32_16x16x32_bf16(al0[ks], bh[ks], accA0, 0, 0, 0);
            accA0 = __builtin_amdgcn_mfma_f32_16x16x32_bf16(ah0[ks], bl[ks], accA0, 0, 0, 0);
            accA1 = __builtin_amdgcn_mfma_f32_16x16x32_bf16(ah1[ks], bh[ks], accA1, 0, 0, 0);
            accA1 = __builtin_amdgcn_mfma_f32_16x16x32_bf16(al1[ks], bh[ks], accA1, 0, 0, 0);
            accA1 = __builtin_amdgcn_mfma_f32_16x16x32_bf16(ah1[ks], bl[ks], accA1, 0, 0, 0);
        }
#pragma unroll
        for (int ks = 2; ks < 4; ++ks) {
            accB0 = __builtin_amdgcn_mfma_f32_16x16x32_bf16(ah0[ks], bh[ks], accB0, 0, 0, 0);
            accB0 = __builtin_amdgcn_mfma_f32_16x16x32_bf16(al0[ks], bh[ks], accB0, 0, 0, 0);
            accB0 = __builtin_amdgcn_mfma_f32_16x16x32_bf16(ah0[ks], bl[ks], accB0, 0, 0, 0);
            accB1 = __builtin_amdgcn_mfma_f32_16x16x32_bf16(ah1[ks], bh[ks], accB1, 0, 0, 0);
            accB1 = __builtin_amdgcn_mfma_f32_16x16x32_bf16(al1[ks], bh[ks], accB1, 0, 0, 0);
            accB1 = __builtin_amdgcn_mfma_f32_16x16x32_bf16(ah1[ks], bl[ks], accB1, 0, 0, 0);
        }
        int c = ct * 16 + m;
        float sE = sumE[c];
#pragma unroll
        for (int r = 0; r < 4; ++r) {
            float s0 = fmaf(-2.f, accA0[r] + accB0[r], sE);
            if (s0 < b1[0][r]) { b2[0][r] = b1[0][r]; b1[0][r] = s0; bi[0][r] = c; }
            else if (s0 < b2[0][r]) b2[0][r] = s0;
            float s1 = fmaf(-2.f, accA1[r] + accB1[r], sE);
            if (s1 < b1[1][r]) { b2[1][r] = b1[1][r]; b1[1][r] = s1; bi[1][r] = c; }
            else if (s1 < b2[1][r]) b2[1][r] = s1;
        }
        __syncthreads();
    }
#undef STAGE
    // merge across the 16 col-lanes (codes)
#pragma unroll
    for (int off = 1; off <= 8; off <<= 1) {
#pragma unroll
        for (int tt = 0; tt < 2; ++tt)
#pragma unroll
            for (int r = 0; r < 4; ++r) {
                float o1 = __shfl_xor(b1[tt][r], off, 64);
                float o2 = __shfl_xor(b2[tt][r], off, 64);
                int oi = __shfl_xor(bi[tt][r], off, 64);
                if (o1 < b1[tt][r] || (o1 == b1[tt][r] && oi < bi[tt][r])) {
                    b2[tt][r] = fminf(b1[tt][r], o2); b1[tt][r] = o1; bi[tt][r] = oi;
                } else {
                    b2[tt][r] = fminf(b2[tt][r], o1);
                }
            }
    }
    float liS = 0.f, mkT = 0.f;
#pragma unroll
    for (int tt = 0; tt < 2; ++tt)
#pragma unroll
        for (int r = 0; r < 4; ++r) {
            int row = kg * 4 + r;
            float mkr = mkS[wid][tt * 16 + row], xnr = xnS[wid][tt * 16 + row];
            liS += mkr * mkr * (xnr + b1[tt][r]);
            mkT += mkr;
            if (m == 0) {
                int tokr = tok0 + tt * 16 + row;
                idx_out[tokr] = bi[tt][r];
                if (b2[tt][r] - b1[tt][r] < MARGIN) {
                    int pp = atomicAdd(flagCnt, 1);
                    flagList[pp] = tokr;
                }
            }
        }
    liS += __shfl_xor(liS, 16, 64);
    liS += __shfl_xor(liS, 32, 64);
    mkT += __shfl_xor(mkT, 16, 64);
    mkT += __shfl_xor(mkT, 32, 64);
    if (lane == 0) {
        int grp = blockIdx.x * 4 + wid;
        lossW[grp] = liS;
        maskW[grp] = mkT;
    }
}

// kF: bit-exact np-f32 rescan for flagged tokens. R20 fix: ONE token per wave
// (R13's 4-token batching serialized 4x the work on the few busy waves while
// 99% of the chip idled: 67 us at Occupancy 1.3%). Grid 1024 blocks = 4096
// waves -> every flagged token gets its own wave in one pass.
__global__ __launch_bounds__(256) void kF(const float* __restrict__ x,
                                          const float* __restrict__ xmask,
                                          const float* __restrict__ embT,
                                          const float* __restrict__ sumE,
                                          const int* __restrict__ flagCnt,
                                          const int* __restrict__ flagList,
                                          int* __restrict__ idx_out) {
    int wave = (blockIdx.x * 256 + threadIdx.x) >> 6;
    int lane = threadIdx.x & 63;
    int nW = gridDim.x * 4;
    int cnt = *flagCnt;
    for (int j = wave; j < cnt; j += nW) {
        int t = flagList[j];
        float mk = xmask[t];
        const float* xr = x + (size_t)t * D_EMB;
        float sx = np_pairwise_sumsq128(xr, mk);
        float acc[8];
#pragma unroll
        for (int cb = 0; cb < 8; ++cb) acc[cb] = 0.f;
        for (int i = 0; i < D_EMB; ++i) {
            float xi = __fmul_rn(xr[i], mk);
#pragma unroll
            for (int cb = 0; cb < 8; ++cb)
                acc[cb] = __fmaf_rn(xi, embT[i * M_CODES + cb * 64 + lane], acc[cb]);
        }
        float best = 3.4e38f;
        int bq = 0x7fffffff;
#pragma unroll
        for (int cb = 0; cb < 8; ++cb) {
            int c = cb * 64 + lane;
            float d = __fsub_rn(__fadd_rn(sumE[c], sx), __fmul_rn(2.f, acc[cb]));
            if (d < best || (d == best && c < bq)) { best = d; bq = c; }
        }
#pragma unroll
        for (int off = 32; off > 0; off >>= 1) {
            float s2 = __shfl_xor(best, off, 64);
            int i2 = __shfl_xor(bq, off, 64);
            if (s2 < best || (s2 == best && i2 < bq)) { best = s2; bq = i2; }
        }
        if (lane == 0) idx_out[t] = bq;
    }
}

// kScat: LDS-accumulated scatter + fused q_st write. (R17-validated.)
__global__ __launch_bounds__(256) void kScat(const float* __restrict__ x,
                                             const float* __restrict__ emb,
                                             const float* __restrict__ xmask,
                                             const int* __restrict__ idx,
                                             float* __restrict__ q_st,
                                             float* __restrict__ partialD,
                                             float* __restrict__ accc,
                                             int N, int nch) {
    __shared__ float accD[16 * M_CODES];   // [dd][code]
    __shared__ float accC[M_CODES];
    int bid = blockIdx.x;
    int q = bid / nch, ch = bid - q * nch;   // q = dim-slice 0..7
    int tid = threadIdx.x;
    for (int i = tid; i < 16 * M_CODES; i += 256) accD[i] = 0.f;
    if (q == 0)
        for (int i = tid; i < M_CODES; i += 256) accC[i] = 0.f;
    __syncthreads();
    int tl = tid >> 1, dl = tid & 1;
    int base = ch * SCHUNK;
    for (int it = 0; it < SCHUNK / 128; ++it) {
        int t = base + it * 128 + tl;
        if (t < N) {
            int id = idx[t];
            float mk = xmask[t];
            const float4* xp = reinterpret_cast<const float4*>(
                x + (size_t)t * D_EMB + q * 16 + dl * 8);
            const float4* ep = reinterpret_cast<const float4*>(
                emb + (size_t)id * D_EMB + q * 16 + dl * 8);
            float4 xv0 = xp[0], xv1 = xp[1];
            float4 ev0 = ep[0], ev1 = ep[1];
            float4 o0, o1;
            o0.x = ev0.x * mk; o0.y = ev0.y * mk; o0.z = ev0.z * mk; o0.w = ev0.w * mk;
            o1.x = ev1.x * mk; o1.y = ev1.y * mk; o1.z = ev1.z * mk; o1.w = ev1.w * mk;
            float4* qp = reinterpret_cast<float4*>(
                q_st + (size_t)t * D_EMB + q * 16 + dl * 8);
            qp[0] = o0; qp[1] = o1;
            float vx[8] = {xv0.x * mk, xv0.y * mk, xv0.z * mk, xv0.w * mk,
                           xv1.x * mk, xv1.y * mk, xv1.z * mk, xv1.w * mk};
            int d0 = dl * 8;
#pragma unroll
            for (int j = 0; j < 8; ++j)
                atomicAdd(&accD[(d0 + j) * M_CODES + id], vx[j]);
            if (q == 0 && dl == 0) atomicAdd(&accC[id], 1.f);
        }
    }
    __syncthreads();
    float* pD = partialD + (size_t)bid * (16 * M_CODES);
    for (int i = tid; i < 16 * M_CODES; i += 256) pD[i] = accD[i];
    if (q == 0)
        for (int i = tid; i < M_CODES; i += 256) atomicAdd(&accc[i], accC[i]);
}

// kC: count normalization + loss finalize.
__global__ __launch_bounds__(512) void kC(const float* __restrict__ counts,
                                          const float* __restrict__ ema_count,
                                          float* __restrict__ new_count_out,
                                          float* __restrict__ norm_ws,
                                          const float* __restrict__ lossP,
                                          const float* __restrict__ maskP,
                                          float* __restrict__ loss_out, int nP) {
    __shared__ float red[512];
    int t = threadIdx.x;
    float raw = 0.999f * ema_count[t] + 0.001f * counts[t];
    red[t] = raw;
    __syncthreads();
#pragma unroll
    for (int s = 256; s > 0; s >>= 1) {
        if (t < s) red[t] += red[t + s];
        __syncthreads();
    }
    float nsum = red[0];
    __syncthreads();
    float norm = (raw + 1e-5f) / (nsum + (float)M_CODES * 1e-5f) * nsum;
    new_count_out[t] = norm;
    norm_ws[t] = norm;

    float lp = 0.f, mp = 0.f;
    for (int i = t; i < nP; i += 512) { lp += lossP[i]; mp += maskP[i]; }
    red[t] = lp;
    __syncthreads();
#pragma unroll
    for (int s = 256; s > 0; s >>= 1) {
        if (t < s) red[t] += red[t + s];
        __syncthreads();
    }
    float S = red[0];
    __syncthreads();
    red[t] = mp;
    __syncthreads();
#pragma unroll
    for (int s = 256; s > 0; s >>= 1) {
        if (t < s) red[t] += red[t + s];
        __syncthreads();
    }
    if (t == 0) loss_out[0] = 0.25f * S / (red[0] * (float)D_EMB);
}

// kWD2: reduce chunk partials + EMA + divide (code-fastest coalesced reads).
__global__ void kWD2(const float* __restrict__ partialD,
                     const float* __restrict__ ema_w,
                     const float* __restrict__ norm_ws,
                     float* __restrict__ new_w, float* __restrict__ new_emb,
                     int nch) {
    int i = blockIdx.x * 256 + threadIdx.x;   // 65536 elements
    int c = i & 511;          // code (fastest)
    int d = i >> 9;           // dim 0..127
    int q = d >> 4, dd = d & 15;
    float s = 0.f;
    for (int ch = 0; ch < nch; ++ch)
        s += partialD[(size_t)(q * nch + ch) * (16 * M_CODES) + dd * M_CODES + c];
    size_t o = (size_t)c * D_EMB + d;
    float w = 0.999f * ema_w[o] + 0.001f * s;
    new_w[o] = w;
    new_emb[o] = w / norm_ws[c];
}

extern "C" void kernel_launch(void* const* d_in, const int* in_sizes, int n_in,
                              void* d_out, int out_size, void* d_ws, size_t ws_size,
                              hipStream_t stream) {
    const float* x = (const float*)d_in[0];
    const float* xmask = (const float*)d_in[1];
    const float* emb = (const float*)d_in[2];
    const float* ema_count = (const float*)d_in[3];
    const float* ema_weight = (const float*)d_in[4];
    int N = in_sizes[0] / D_EMB;

    float* out = (float*)d_out;
    float* q_st = out;
    float* loss = out + (size_t)N * D_EMB;
    float* new_emb = loss + 1;
    float* new_cnt = new_emb + M_CODES * D_EMB;
    float* new_w = new_cnt + M_CODES;

    int nGrp = N / 32;                         // 2048 wave groups
    int nch = (N + SCHUNK - 1) / SCHUNK;       // 64
    float* fws = (float*)d_ws;
    int* idx = (int*)fws;                      // N
    float* counts = fws + N;                   // 512 (accc)
    float* norm = counts + M_CODES;            // 512
    float* lossP = norm + M_CODES;             // nGrp
    float* maskP = lossP + nGrp;               // nGrp
    float* sumE = maskP + nGrp;                // 512
    int* flagCnt = (int*)(sumE + M_CODES);     // 4
    int* flagList = flagCnt + 4;               // N
    float* embT = (float*)(flagList + N);      // 65536
    unsigned short* ebh = (unsigned short*)(embT + M_CODES * D_EMB);  // 65536 u16
    unsigned short* ebl = ebh + M_CODES * D_EMB;                      // 65536 u16
    float* partialD = (float*)(ebl + M_CODES * D_EMB);  // 8*nch*16*512 f32 (16MB)

    hipLaunchKernelGGL(kSZ, dim3(128), dim3(256), 0, stream,
                       emb, sumE, embT, ebh, ebl, counts, flagCnt);
    hipLaunchKernelGGL(kA, dim3(N / 128), dim3(256), 0, stream, x, xmask, ebh,
                       ebl, sumE, idx, flagCnt, flagList, lossP, maskP, N);
    hipLaunchKernelGGL(kF, dim3(1024), dim3(256), 0, stream, x, xmask, embT, sumE,
                       flagCnt, flagList, idx);
    hipLaunchKernelGGL(kScat, dim3(8 * nch), dim3(256), 0, stream, x, emb, xmask,
                       idx, q_st, partialD, counts, N, nch);
    hipLaunchKernelGGL(kC, dim3(1), dim3(512), 0, stream, counts, ema_count,
                       new_cnt, norm, lossP, maskP, loss, nGrp);
    hipLaunchKernelGGL(kWD2, dim3(M_CODES * D_EMB / 256), dim3(256), 0, stream,
                       partialD, ema_weight, norm, new_w, new_emb, nch);
}

// Round 22
// 133.709 us; speedup vs baseline: 3.2810x; 1.1480x over previous
//
#include <hip/hip_runtime.h>

#define M_CODES 512
#define D_EMB 128
#define D4 32
#define MARGIN 5e-5f
#define SCHUNK 1024   // tokens per scatter chunk

typedef short bf16x8 __attribute__((ext_vector_type(8)));
typedef float f32x4 __attribute__((ext_vector_type(4)));

__device__ __forceinline__ unsigned short f2bf(float f) {  // RNE f32->bf16
    unsigned u = __float_as_uint(f);
    u += 0x7fffu + ((u >> 16) & 1u);
    return (unsigned short)(u >> 16);
}
__device__ __forceinline__ float bf2f(unsigned short h) {
    return __uint_as_float(((unsigned)h) << 16);
}

// numpy pairwise sum (n=128): 8 strided accumulators + tree. (R6-validated.)
__device__ __forceinline__ float np_pairwise_sumsq128(const float* __restrict__ a,
                                                      float scale) {
    float r[8];
#pragma unroll
    for (int j = 0; j < 8; ++j) {
        float v = __fmul_rn(a[j], scale);
        r[j] = __fmul_rn(v, v);
    }
    for (int i = 8; i < 128; i += 8) {
#pragma unroll
        for (int j = 0; j < 8; ++j) {
            float v = __fmul_rn(a[i + j], scale);
            r[j] = __fadd_rn(r[j], __fmul_rn(v, v));
        }
    }
    return __fadd_rn(__fadd_rn(__fadd_rn(r[0], r[1]), __fadd_rn(r[2], r[3])),
                     __fadd_rn(__fadd_rn(r[4], r[5]), __fadd_rn(r[6], r[7])));
}

// kSZ: parallel setup (R17-validated).
__global__ __launch_bounds__(256) void kSZ(const float* __restrict__ emb,
                                           float* __restrict__ sumE,
                                           float* __restrict__ embT,
                                           unsigned short* __restrict__ ebh,
                                           unsigned short* __restrict__ ebl,
                                           float* __restrict__ accc,
                                           int* __restrict__ flagCnt) {
    int tid = threadIdx.x, wid = tid >> 6, lane = tid & 63;
    int m = blockIdx.x * 4 + wid;            // 0..511
    int gi = blockIdx.x * 256 + tid;
    if (gi < M_CODES) accc[gi] = 0.f;
    if (gi == 0) *flagCnt = 0;
    const float* er = emb + (size_t)m * D_EMB;
    float r = 0.f;
    if (lane < 8) {
        float v = __fmul_rn(er[lane], 1.0f);
        r = __fmul_rn(v, v);
        for (int i = 1; i < 16; ++i) {
            float w = __fmul_rn(er[8 * i + lane], 1.0f);
            r = __fadd_rn(r, __fmul_rn(w, w));
        }
    }
    float s1 = __fadd_rn(r, __shfl_xor(r, 1, 64));
    float s2 = __fadd_rn(s1, __shfl_xor(s1, 2, 64));
    float s3 = __fadd_rn(s2, __shfl_xor(s2, 4, 64));
    if (lane == 0) sumE[m] = s3;
#pragma unroll
    for (int dd = lane; dd < D_EMB; dd += 64) {
        float e = er[dd];
        embT[dd * M_CODES + m] = e;
        unsigned short hh = f2bf(e);
        ebh[(size_t)m * D_EMB + dd] = hh;
        ebl[(size_t)m * D_EMB + dd] = f2bf(e - bf2f(hh));
    }
}

// kA: split-bf16 MFMA + LDS-staged codebook. R21 evolution: 32-code tiles
// (16 barriers instead of 32; 48 MFMA per wave per barrier) + T14 async-stage
// split (issue loads BEFORE compute, ds_write AFTER -> L2 latency hides under
// the MFMA block). Swizzle maps identical to R20-validated per 16-code subtile.
__global__ __launch_bounds__(256) void kA(const float* __restrict__ x,
                                          const float* __restrict__ xmask,
                                          const unsigned short* __restrict__ ebh,
                                          const unsigned short* __restrict__ ebl,
                                          const float* __restrict__ sumE,
                                          int* __restrict__ idx_out,
                                          int* __restrict__ flagCnt,
                                          int* __restrict__ flagList,
                                          float* __restrict__ lossW,
                                          float* __restrict__ maskW, int N) {
    __shared__ unsigned short hb[2][4096];   // 8 KB per buf: 32 codes x 128d
    __shared__ unsigned short lb[2][4096];
    __shared__ float xnS[4][32], mkS[4][32];
    int tid = threadIdx.x;
    int wid = tid >> 6, lane = tid & 63;
    int m = lane & 15, kg = lane >> 4;
    int tok0 = blockIdx.x * 128 + wid * 32;

    // ---- A fragments: 32 tokens (two 16-token tiles), split-bf16 ----
    bf16x8 ah0[4], al0[4], ah1[4], al1[4];
    float xn0 = 0.f, xn1 = 0.f;
    float mk0 = xmask[tok0 + m], mk1 = xmask[tok0 + 16 + m];
#pragma unroll
    for (int ks = 0; ks < 4; ++ks) {
        const float4* p0 = reinterpret_cast<const float4*>(
            x + (size_t)(tok0 + m) * D_EMB + ks * 32 + kg * 8);
        const float4* p1 = reinterpret_cast<const float4*>(
            x + (size_t)(tok0 + 16 + m) * D_EMB + ks * 32 + kg * 8);
        float4 a0 = p0[0], a1 = p0[1], c0 = p1[0], c1 = p1[1];
        float e0[8] = {a0.x, a0.y, a0.z, a0.w, a1.x, a1.y, a1.z, a1.w};
        float e1[8] = {c0.x, c0.y, c0.z, c0.w, c1.x, c1.y, c1.z, c1.w};
        bf16x8 h0, l0, h1, l1;
#pragma unroll
        for (int j = 0; j < 8; ++j) {
            float v0 = e0[j] * mk0;
            xn0 = fmaf(v0, v0, xn0);
            unsigned short hh0 = f2bf(v0);
            h0[j] = (short)hh0;
            l0[j] = (short)f2bf(v0 - bf2f(hh0));
            float v1 = e1[j] * mk1;
            xn1 = fmaf(v1, v1, xn1);
            unsigned short hh1 = f2bf(v1);
            h1[j] = (short)hh1;
            l1[j] = (short)f2bf(v1 - bf2f(hh1));
        }
        ah0[ks] = h0; al0[ks] = l0; ah1[ks] = h1; al1[ks] = l1;
    }
    xn0 += __shfl_xor(xn0, 16, 64);
    xn0 += __shfl_xor(xn0, 32, 64);
    xn1 += __shfl_xor(xn1, 16, 64);
    xn1 += __shfl_xor(xn1, 32, 64);
    if (kg == 0) {
        xnS[wid][m] = xn0; mkS[wid][m] = mk0;
        xnS[wid][16 + m] = xn1; mkS[wid][16 + m] = mk1;
    }

    float b1[2][4], b2[2][4];
    int bi[2][4];
#pragma unroll
    for (int tt = 0; tt < 2; ++tt)
#pragma unroll
        for (int r = 0; r < 4; ++r) {
            b1[tt][r] = 3.4e38f; b2[tt][r] = 3.4e38f; bi[tt][r] = 0x7fffffff;
        }

    // staging: thread -> (code mo = tid>>4, 16B-slot sl = tid&15), 2 subtiles
    int mo = tid >> 4, sl = tid & 15;
    int dstIdx = mo * 128 + (sl >> 3) * 64 + ((sl & 7) ^ (mo & 7)) * 8;  // ushorts
    float4 sh0, sv0, sh1, sv1;  // staging regs (subtile 0/1, h/l)
#define LOADREGS(t)                                                            \
    {                                                                          \
        sh0 = *reinterpret_cast<const float4*>(                                \
            ebh + (size_t)((t) * 32 + mo) * D_EMB + sl * 8);                   \
        sv0 = *reinterpret_cast<const float4*>(                                \
            ebl + (size_t)((t) * 32 + mo) * D_EMB + sl * 8);                   \
        sh1 = *reinterpret_cast<const float4*>(                                \
            ebh + (size_t)((t) * 32 + 16 + mo) * D_EMB + sl * 8);              \
        sv1 = *reinterpret_cast<const float4*>(                                \
            ebl + (size_t)((t) * 32 + 16 + mo) * D_EMB + sl * 8);              \
    }
#define WRITEB(b)                                                              \
    {                                                                          \
        *reinterpret_cast<float4*>(&hb[b][dstIdx]) = sh0;                      \
        *reinterpret_cast<float4*>(&lb[b][dstIdx]) = sv0;                      \
        *reinterpret_cast<float4*>(&hb[b][2048 + dstIdx]) = sh1;               \
        *reinterpret_cast<float4*>(&lb[b][2048 + dstIdx]) = sv1;               \
    }

    LOADREGS(0);
    WRITEB(0);
    __syncthreads();
    for (int t = 0; t < 16; ++t) {
        int cur = t & 1;
        if (t < 15) LOADREGS(t + 1);   // issue early (T14)
#pragma unroll
        for (int sub = 0; sub < 2; ++sub) {
            bf16x8 bh[4], bl[4];
#pragma unroll
            for (int ks = 0; ks < 4; ++ks) {
                int off = sub * 2048 + m * 128 + (ks >> 1) * 64 +
                          ((((ks & 1) * 4 + kg)) ^ (m & 7)) * 8;
                bh[ks] = *reinterpret_cast<const bf16x8*>(&hb[cur][off]);
                bl[ks] = *reinterpret_cast<const bf16x8*>(&lb[cur][off]);
            }
            f32x4 accA0 = {0.f, 0.f, 0.f, 0.f}, accB0 = {0.f, 0.f, 0.f, 0.f};
            f32x4 accA1 = {0.f, 0.f, 0.f, 0.f}, accB1 = {0.f, 0.f, 0.f, 0.f};
#pragma unroll
            for (int ks = 0; ks < 2; ++ks) {
                accA0 = __builtin_amdgcn_mfma_f32_16x16x32_bf16(ah0[ks], bh[ks], accA0, 0, 0, 0);
                accA0 = __builtin_amdgcn_mfma_f32_16x16x32_bf16(al0[ks], bh[ks], accA0, 0, 0, 0);
                accA0 = __builtin_amdgcn_mfma_f32_16x16x32_bf16(ah0[ks], bl[ks], accA0, 0, 0, 0);
                accA1 = __builtin_amdgcn_mfma_f32_16x16x32_bf16(ah1[ks], bh[ks], accA1, 0, 0, 0);
                accA1 = __builtin_amdgcn_mfma_f32_16x16x32_bf16(al1[ks], bh[ks], accA1, 0, 0, 0);
                accA1 = __builtin_amdgcn_mfma_f32_16x16x32_bf16(ah1[ks], bl[ks], accA1, 0, 0, 0);
            }
#pragma unroll
            for (int ks = 2; ks < 4; ++ks) {
                accB0 = __builtin_amdgcn_mfma_f32_16x16x32_bf16(ah0[ks], bh[ks], accB0, 0, 0, 0);
                accB0 = __builtin_amdgcn_mfma_f32_16x16x32_bf16(al0[ks], bh[ks], accB0, 0, 0, 0);
                accB0 = __builtin_amdgcn_mfma_f32_16x16x32_bf16(ah0[ks], bl[ks], accB0, 0, 0, 0);
                accB1 = __builtin_amdgcn_mfma_f32_16x16x32_bf16(ah1[ks], bh[ks], accB1, 0, 0, 0);
                accB1 = __builtin_amdgcn_mfma_f32_16x16x32_bf16(al1[ks], bh[ks], accB1, 0, 0, 0);
                accB1 = __builtin_amdgcn_mfma_f32_16x16x32_bf16(ah1[ks], bl[ks], accB1, 0, 0, 0);
            }
            int c = t * 32 + sub * 16 + m;
            float sE = sumE[c];
#pragma unroll
            for (int r = 0; r < 4; ++r) {
                float s0 = fmaf(-2.f, accA0[r] + accB0[r], sE);
                if (s0 < b1[0][r]) { b2[0][r] = b1[0][r]; b1[0][r] = s0; bi[0][r] = c; }
                else if (s0 < b2[0][r]) b2[0][r] = s0;
                float s1 = fmaf(-2.f, accA1[r] + accB1[r], sE);
                if (s1 < b1[1][r]) { b2[1][r] = b1[1][r]; b1[1][r] = s1; bi[1][r] = c; }
                else if (s1 < b2[1][r]) b2[1][r] = s1;
            }
        }
        if (t < 15) WRITEB(cur ^ 1);   // write late (vmcnt hidden under MFMA)
        __syncthreads();
    }
#undef LOADREGS
#undef WRITEB
    // merge across the 16 col-lanes (codes)
#pragma unroll
    for (int off = 1; off <= 8; off <<= 1) {
#pragma unroll
        for (int tt = 0; tt < 2; ++tt)
#pragma unroll
            for (int r = 0; r < 4; ++r) {
                float o1 = __shfl_xor(b1[tt][r], off, 64);
                float o2 = __shfl_xor(b2[tt][r], off, 64);
                int oi = __shfl_xor(bi[tt][r], off, 64);
                if (o1 < b1[tt][r] || (o1 == b1[tt][r] && oi < bi[tt][r])) {
                    b2[tt][r] = fminf(b1[tt][r], o2); b1[tt][r] = o1; bi[tt][r] = oi;
                } else {
                    b2[tt][r] = fminf(b2[tt][r], o1);
                }
            }
    }
    float liS = 0.f, mkT = 0.f;
#pragma unroll
    for (int tt = 0; tt < 2; ++tt)
#pragma unroll
        for (int r = 0; r < 4; ++r) {
            int row = kg * 4 + r;
            float mkr = mkS[wid][tt * 16 + row], xnr = xnS[wid][tt * 16 + row];
            liS += mkr * mkr * (xnr + b1[tt][r]);
            mkT += mkr;
            if (m == 0) {
                int tokr = tok0 + tt * 16 + row;
                idx_out[tokr] = bi[tt][r];
                if (b2[tt][r] - b1[tt][r] < MARGIN) {
                    int pp = atomicAdd(flagCnt, 1);
                    flagList[pp] = tokr;
                }
            }
        }
    liS += __shfl_xor(liS, 16, 64);
    liS += __shfl_xor(liS, 32, 64);
    mkT += __shfl_xor(mkT, 16, 64);
    mkT += __shfl_xor(mkT, 32, 64);
    if (lane == 0) {
        int grp = blockIdx.x * 4 + wid;
        lossW[grp] = liS;
        maskW[grp] = mkT;
    }
}

// kF: bit-exact np-f32 rescan, one token per wave. (R21-validated.)
__global__ __launch_bounds__(256) void kF(const float* __restrict__ x,
                                          const float* __restrict__ xmask,
                                          const float* __restrict__ embT,
                                          const float* __restrict__ sumE,
                                          const int* __restrict__ flagCnt,
                                          const int* __restrict__ flagList,
                                          int* __restrict__ idx_out) {
    int wave = (blockIdx.x * 256 + threadIdx.x) >> 6;
    int lane = threadIdx.x & 63;
    int nW = gridDim.x * 4;
    int cnt = *flagCnt;
    for (int j = wave; j < cnt; j += nW) {
        int t = flagList[j];
        float mk = xmask[t];
        const float* xr = x + (size_t)t * D_EMB;
        float sx = np_pairwise_sumsq128(xr, mk);
        float acc[8];
#pragma unroll
        for (int cb = 0; cb < 8; ++cb) acc[cb] = 0.f;
        for (int i = 0; i < D_EMB; ++i) {
            float xi = __fmul_rn(xr[i], mk);
#pragma unroll
            for (int cb = 0; cb < 8; ++cb)
                acc[cb] = __fmaf_rn(xi, embT[i * M_CODES + cb * 64 + lane], acc[cb]);
        }
        float best = 3.4e38f;
        int bq = 0x7fffffff;
#pragma unroll
        for (int cb = 0; cb < 8; ++cb) {
            int c = cb * 64 + lane;
            float d = __fsub_rn(__fadd_rn(sumE[c], sx), __fmul_rn(2.f, acc[cb]));
            if (d < best || (d == best && c < bq)) { best = d; bq = c; }
        }
#pragma unroll
        for (int off = 32; off > 0; off >>= 1) {
            float s2 = __shfl_xor(best, off, 64);
            int i2 = __shfl_xor(bq, off, 64);
            if (s2 < best || (s2 == best && i2 < bq)) { best = s2; bq = i2; }
        }
        if (lane == 0) idx_out[t] = bq;
    }
}

// kScat: LDS-accumulated scatter + fused q_st write. (R17-validated.)
__global__ __launch_bounds__(256) void kScat(const float* __restrict__ x,
                                             const float* __restrict__ emb,
                                             const float* __restrict__ xmask,
                                             const int* __restrict__ idx,
                                             float* __restrict__ q_st,
                                             float* __restrict__ partialD,
                                             float* __restrict__ accc,
                                             int N, int nch) {
    __shared__ float accD[16 * M_CODES];   // [dd][code]
    __shared__ float accC[M_CODES];
    int bid = blockIdx.x;
    int q = bid / nch, ch = bid - q * nch;   // q = dim-slice 0..7
    int tid = threadIdx.x;
    for (int i = tid; i < 16 * M_CODES; i += 256) accD[i] = 0.f;
    if (q == 0)
        for (int i = tid; i < M_CODES; i += 256) accC[i] = 0.f;
    __syncthreads();
    int tl = tid >> 1, dl = tid & 1;
    int base = ch * SCHUNK;
    for (int it = 0; it < SCHUNK / 128; ++it) {
        int t = base + it * 128 + tl;
        if (t < N) {
            int id = idx[t];
            float mk = xmask[t];
            const float4* xp = reinterpret_cast<const float4*>(
                x + (size_t)t * D_EMB + q * 16 + dl * 8);
            const float4* ep = reinterpret_cast<const float4*>(
                emb + (size_t)id * D_EMB + q * 16 + dl * 8);
            float4 xv0 = xp[0], xv1 = xp[1];
            float4 ev0 = ep[0], ev1 = ep[1];
            float4 o0, o1;
            o0.x = ev0.x * mk; o0.y = ev0.y * mk; o0.z = ev0.z * mk; o0.w = ev0.w * mk;
            o1.x = ev1.x * mk; o1.y = ev1.y * mk; o1.z = ev1.z * mk; o1.w = ev1.w * mk;
            float4* qp = reinterpret_cast<float4*>(
                q_st + (size_t)t * D_EMB + q * 16 + dl * 8);
            qp[0] = o0; qp[1] = o1;
            float vx[8] = {xv0.x * mk, xv0.y * mk, xv0.z * mk, xv0.w * mk,
                           xv1.x * mk, xv1.y * mk, xv1.z * mk, xv1.w * mk};
            int d0 = dl * 8;
#pragma unroll
            for (int j = 0; j < 8; ++j)
                atomicAdd(&accD[(d0 + j) * M_CODES + id], vx[j]);
            if (q == 0 && dl == 0) atomicAdd(&accC[id], 1.f);
        }
    }
    __syncthreads();
    float* pD = partialD + (size_t)bid * (16 * M_CODES);
    for (int i = tid; i < 16 * M_CODES; i += 256) pD[i] = accD[i];
    if (q == 0)
        for (int i = tid; i < M_CODES; i += 256) atomicAdd(&accc[i], accC[i]);
}

// kWD2: fused finalize (R21: kC eliminated — serial 1-block link). Per block:
// recompute nsum via LDS tree (cheap, deterministic), norm on the fly; reduce
// chunk partials + EMA + divide; d==0 threads write new_cnt; block 0 also
// finalizes the loss from lossP/maskP.
__global__ __launch_bounds__(256) void kWD2(const float* __restrict__ partialD,
                                            const float* __restrict__ ema_w,
                                            const float* __restrict__ counts,
                                            const float* __restrict__ ema_count,
                                            const float* __restrict__ lossP,
                                            const float* __restrict__ maskP,
                                            float* __restrict__ new_w,
                                            float* __restrict__ new_emb,
                                            float* __restrict__ new_cnt,
                                            float* __restrict__ loss_out,
                                            int nch, int nP) {
    __shared__ float red[256];
    int tid = threadIdx.x;
    float part = 0.999f * ema_count[tid] + 0.001f * counts[tid];
    part += 0.999f * ema_count[tid + 256] + 0.001f * counts[tid + 256];
    red[tid] = part;
    __syncthreads();
#pragma unroll
    for (int s = 128; s > 0; s >>= 1) {
        if (tid < s) red[tid] += red[tid + s];
        __syncthreads();
    }
    float nsum = red[0];
    __syncthreads();

    int i = blockIdx.x * 256 + tid;   // 65536 elements
    int c = i & 511;                  // code (fastest)
    int d = i >> 9;                   // dim 0..127
    int q = d >> 4, dd = d & 15;
    float raw = 0.999f * ema_count[c] + 0.001f * counts[c];
    float norm = (raw + 1e-5f) / (nsum + (float)M_CODES * 1e-5f) * nsum;
    float s = 0.f;
    for (int ch = 0; ch < nch; ++ch)
        s += partialD[(size_t)(q * nch + ch) * (16 * M_CODES) + dd * M_CODES + c];
    size_t o = (size_t)c * D_EMB + d;
    float w = 0.999f * ema_w[o] + 0.001f * s;
    new_w[o] = w;
    new_emb[o] = w / norm;
    if (d == 0) new_cnt[c] = norm;

    if (blockIdx.x == 0) {
        float lp = 0.f, mp = 0.f;
        for (int j = tid; j < nP; j += 256) { lp += lossP[j]; mp += maskP[j]; }
        red[tid] = lp;
        __syncthreads();
#pragma unroll
        for (int ss = 128; ss > 0; ss >>= 1) {
            if (tid < ss) red[tid] += red[tid + ss];
            __syncthreads();
        }
        float S = red[0];
        __syncthreads();
        red[tid] = mp;
        __syncthreads();
#pragma unroll
        for (int ss = 128; ss > 0; ss >>= 1) {
            if (tid < ss) red[tid] += red[tid + ss];
            __syncthreads();
        }
        if (tid == 0) loss_out[0] = 0.25f * S / (red[0] * (float)D_EMB);
    }
}

extern "C" void kernel_launch(void* const* d_in, const int* in_sizes, int n_in,
                              void* d_out, int out_size, void* d_ws, size_t ws_size,
                              hipStream_t stream) {
    const float* x = (const float*)d_in[0];
    const float* xmask = (const float*)d_in[1];
    const float* emb = (const float*)d_in[2];
    const float* ema_count = (const float*)d_in[3];
    const float* ema_weight = (const float*)d_in[4];
    int N = in_sizes[0] / D_EMB;

    float* out = (float*)d_out;
    float* q_st = out;
    float* loss = out + (size_t)N * D_EMB;
    float* new_emb = loss + 1;
    float* new_cnt = new_emb + M_CODES * D_EMB;
    float* new_w = new_cnt + M_CODES;

    int nGrp = N / 32;                         // 2048 wave groups
    int nch = (N + SCHUNK - 1) / SCHUNK;       // 64
    float* fws = (float*)d_ws;
    int* idx = (int*)fws;                      // N
    float* counts = fws + N;                   // 512 (accc)
    float* norm = counts + M_CODES;            // 512 (unused; layout keep)
    float* lossP = norm + M_CODES;             // nGrp
    float* maskP = lossP + nGrp;               // nGrp
    float* sumE = maskP + nGrp;                // 512
    int* flagCnt = (int*)(sumE + M_CODES);     // 4
    int* flagList = flagCnt + 4;               // N
    float* embT = (float*)(flagList + N);      // 65536
    unsigned short* ebh = (unsigned short*)(embT + M_CODES * D_EMB);  // 65536 u16
    unsigned short* ebl = ebh + M_CODES * D_EMB;                      // 65536 u16
    float* partialD = (float*)(ebl + M_CODES * D_EMB);  // 8*nch*16*512 f32 (16MB)

    hipLaunchKernelGGL(kSZ, dim3(128), dim3(256), 0, stream,
                       emb, sumE, embT, ebh, ebl, counts, flagCnt);
    hipLaunchKernelGGL(kA, dim3(N / 128), dim3(256), 0, stream, x, xmask, ebh,
                       ebl, sumE, idx, flagCnt, flagList, lossP, maskP, N);
    hipLaunchKernelGGL(kF, dim3(1024), dim3(256), 0, stream, x, xmask, embT, sumE,
                       flagCnt, flagList, idx);
    hipLaunchKernelGGL(kScat, dim3(8 * nch), dim3(256), 0, stream, x, emb, xmask,
                       idx, q_st, partialD, counts, N, nch);
    hipLaunchKernelGGL(kWD2, dim3(M_CODES * D_EMB / 256), dim3(256), 0, stream,
                       partialD, ema_weight, counts, ema_count, lossP, maskP,
                       new_w, new_emb, new_cnt, loss, nch, nGrp);
}